// Round 3
// baseline (2693.696 us; speedup 1.0000x reference)
//
#include <hip/hip_runtime.h>
#include <hip/hip_bf16.h>
#include <math.h>

#define LAYERS 32
#define H      1024
#define H3     3072
#define NHEADS 16
#define HDIM   64
#define FF     2048
#define BATCH  2
#define SEQ    2048
#define EPSF   1e-6f
#define NSTG   160
#define CNT_INTS (NSTG * 64 * 16)
#define FLG_INTS (NSTG * 8 * 16)

__constant__ int d_KIND[LAYERS] = {0,1,2,3,0,1,2,0,1,2,3,0,1,2,0,1,2,3,0,1,2,0,1,2,3,0,1,2,0,1,2,3};

__device__ __forceinline__ float wredSum(float v) {
#pragma unroll
  for (int m = 32; m >= 1; m >>= 1) v += __shfl_xor(v, m, 64);
  return v;
}
__device__ __forceinline__ int iwredSum(int v) {
#pragma unroll
  for (int m = 32; m >= 1; m >>= 1) v += __shfl_xor(v, m, 64);
  return v;
}
__device__ __forceinline__ float wredMax(float v) {
#pragma unroll
  for (int m = 32; m >= 1; m >>= 1) v = fmaxf(v, __shfl_xor(v, m, 64));
  return v;
}
__device__ __forceinline__ float gelu_t(float x) {
  return 0.5f * x * (1.0f + tanhf(0.7978845608028654f * (x + 0.044715f * x * x * x)));
}

struct NS   { float xe[2][1024]; float red[16]; float scl[2]; float p[6][4][2]; };
struct W2S  { float hs[2][2048]; float pr[2][8][2]; };
struct OUTS { float ys[2][1024]; float pr[2][4][2]; };
struct ATTS { float q[64]; float k[64]; float v[64]; float e[128]; float red[16]; float osum[8][64]; };
union SH { NS ns; W2S w2; OUTS o; ATTS att; };

struct MegaArgs {
  const float* x0; const int* posp;
  const float* n1; const float* n2;
  const float* pW; const float* pb; const float* oW; const float* ob;
  const float* W1; const float* W2;
  const float* sfc; const float* sfd; const float* mix0; const float* mix1;
  const float* kc; const float* vc; const float* cosT; const float* sinT;
  float* z; float* y; float* xA; float* xB; float* xM; float* h; float* attP;
  int* bar; float* out; int nwg;
};

// ---------------------------------------------------------------------------
// grid barrier: 64-line spread arrival counters, wave-parallel leader detect,
// 8-line replicated release flags, s_sleep backoff on spin.
// ---------------------------------------------------------------------------
__device__ __forceinline__ void gridbar(int* bar, int st, int wg, int nwg) {
  __syncthreads();
  int tid = threadIdx.x;
  int* cnt  = bar + (size_t)st * 64 * 16;
  int* flag = bar + CNT_INTS + (size_t)st * 8 * 16;
  if (wg == 0) {
    if (tid == 0)
      __hip_atomic_fetch_add(&cnt[0], 1, __ATOMIC_RELEASE, __HIP_MEMORY_SCOPE_AGENT);
    if (tid < 64) {
      int s;
      do {
        int v = __hip_atomic_load(&cnt[tid * 16], __ATOMIC_RELAXED, __HIP_MEMORY_SCOPE_AGENT);
        s = iwredSum(v);
      } while (s < nwg);
      __builtin_amdgcn_fence(__ATOMIC_ACQUIRE, "agent");
      if (tid < 8)
        __hip_atomic_store(&flag[tid * 16], 1, __ATOMIC_RELEASE, __HIP_MEMORY_SCOPE_AGENT);
    }
  } else {
    if (tid == 0) {
      __hip_atomic_fetch_add(&cnt[(wg & 63) * 16], 1, __ATOMIC_RELEASE, __HIP_MEMORY_SCOPE_AGENT);
      while (__hip_atomic_load(&flag[(wg & 7) * 16], __ATOMIC_RELAXED, __HIP_MEMORY_SCOPE_AGENT) == 0)
        __builtin_amdgcn_s_sleep(1);
      __builtin_amdgcn_fence(__ATOMIC_ACQUIRE, "agent");
    }
  }
  __syncthreads();
}

// ---------------------------------------------------------------------------
// register weight tiles + loaders (addresses static per (stage, rb))
// ---------------------------------------------------------------------------
struct TP { float4 w[3]; };
struct TO { float4 w; };
struct T1 { float4 w[2]; };
struct T2 { float4 w[2]; };

__device__ __forceinline__ TP loadP(const MegaArgs& a, int layer, int kind, int rb) {
  int tid = threadIdx.x, lane = tid & 63, wave = tid >> 6;
  const float* W = a.pW + (size_t)layer * H3 * H;
  int n = rb >> 5, d0 = (rb & 31) << 1;
  TP t;
#pragma unroll
  for (int k = 0; k < 3; k++) {
    int tt = wave + 8 * k, j = tt >> 2, ch = tt & 3;
    int grow = (kind == 3) ? (rb * 6 + j) : (n * 192 + (j >> 1) * 64 + d0 + (j & 1));
    t.w[k] = *(const float4*)(W + (size_t)grow * H + (ch << 8) + (lane << 2));
  }
  return t;
}
__device__ __forceinline__ TO loadOut(const MegaArgs& a, int layer, int rb) {
  int tid = threadIdx.x, lane = tid & 63, wave = tid >> 6;
  const float* W = a.oW + (size_t)layer * H * H;
  int j = wave >> 2, ch = wave & 3;
  TO t;
  t.w = *(const float4*)(W + (size_t)(rb * 2 + j) * H + (ch << 8) + (lane << 2));
  return t;
}
__device__ __forceinline__ T1 loadW1(const MegaArgs& a, int layer, int rb) {
  int tid = threadIdx.x, lane = tid & 63, wave = tid >> 6;
  const float* W = a.W1 + (size_t)layer * FF * H;
  T1 t;
#pragma unroll
  for (int k = 0; k < 2; k++) {
    int tt = wave + 8 * k, j = tt >> 2, ch = tt & 3;
    t.w[k] = *(const float4*)(W + (size_t)(rb * 4 + j) * H + (ch << 8) + (lane << 2));
  }
  return t;
}
__device__ __forceinline__ T2 loadW2(const MegaArgs& a, int layer, int rb) {
  int tid = threadIdx.x, lane = tid & 63, wave = tid >> 6;
  const float* W = a.W2 + (size_t)layer * H * FF;
  T2 t;
#pragma unroll
  for (int k = 0; k < 2; k++) {
    int tt = wave + 8 * k, j = tt >> 3, ch = tt & 7;
    t.w[k] = *(const float4*)(W + (size_t)(rb * 2 + j) * FF + (ch << 8) + (lane << 2));
  }
  return t;
}

// ---------------------------------------------------------------------------
__device__ __forceinline__ void block_norm(const float* __restrict__ xin,
                                           const float* __restrict__ nw, SH& sh) {
  int tid = threadIdx.x, lane = tid & 63, wave = tid >> 6;
  float4 xv = ((const float4*)xin)[tid];
  int b = tid >> 8, ci = tid & 255;
  float4 nv = ((const float4*)nw)[ci];
  float ss = xv.x * xv.x + xv.y * xv.y + xv.z * xv.z + xv.w * xv.w;
  ((float4*)&sh.ns.xe[b][ci << 2])[0] =
      make_float4(xv.x * nv.x, xv.y * nv.y, xv.z * nv.z, xv.w * nv.w);
  ss = wredSum(ss);
  if (lane == 0) sh.ns.red[wave] = ss;
  __syncthreads();
  if (threadIdx.x == 0) {
    sh.ns.scl[0] = rsqrtf((sh.ns.red[0] + sh.ns.red[1] + sh.ns.red[2] + sh.ns.red[3]) * (1.0f / 1024.f) + EPSF);
    sh.ns.scl[1] = rsqrtf((sh.ns.red[4] + sh.ns.red[5] + sh.ns.red[6] + sh.ns.red[7]) * (1.0f / 1024.f) + EPSF);
  }
  __syncthreads();
}

// ---------------------------------------------------------------------------
__device__ __forceinline__ void stageP_rb(const MegaArgs& a, SH& sh, int layer,
                                          int kind, int rb, const TP& tp) {
  const float* pb = a.pb + layer * H3;
  const float* sfcL = a.sfc + (size_t)layer * H3;
  const float* sfdL = a.sfd + (size_t)layer * 2 * H3;
  const float* mix0L = a.mix0 + (size_t)layer * 2 * H;
  const float* mix1L = a.mix1 + (size_t)layer * H;
  int tid = threadIdx.x, lane = tid & 63, wave = tid >> 6;
  int n = rb >> 5, d0 = (rb & 31) << 1;
  float part[3][2];
#pragma unroll
  for (int k = 0; k < 3; k++) {
    int ch = (wave + 8 * k) & 3;
    float4 xa = *(const float4*)&sh.ns.xe[0][(ch << 8) + (lane << 2)];
    float4 xb = *(const float4*)&sh.ns.xe[1][(ch << 8) + (lane << 2)];
    part[k][0] = tp.w[k].x * xa.x + tp.w[k].y * xa.y + tp.w[k].z * xa.z + tp.w[k].w * xa.w;
    part[k][1] = tp.w[k].x * xb.x + tp.w[k].y * xb.y + tp.w[k].z * xb.z + tp.w[k].w * xb.w;
  }
#pragma unroll
  for (int k = 0; k < 3; k++) {
    float s0 = wredSum(part[k][0]);
    float s1 = wredSum(part[k][1]);
    int tt = wave + 8 * k, j = tt >> 2, ch = tt & 3;
    if (lane == 0) { sh.ns.p[j][ch][0] = s0; sh.ns.p[j][ch][1] = s1; }
  }
  __syncthreads();
  if (wave == 0) {
    if (lane < 48) {
      int j = lane >> 3, b = (lane >> 2) & 1, ch = lane & 3;
      float v = sh.ns.p[j][ch][b];
      v += __shfl_xor(v, 1, 64);
      v += __shfl_xor(v, 2, 64);
      if (ch == 0) {
        int grow = (kind == 3) ? (rb * 6 + j) : (n * 192 + (j >> 1) * 64 + d0 + (j & 1));
        float zraw = v * sh.ns.scl[b] + pb[grow];
        if (kind == 3) {
          a.z[b * H3 + grow] = zraw;
        } else {
          sh.ns.p[j][0][b] = sfcL[grow] * zraw + sfdL[b * H3 + grow];
        }
      }
    }
    if (kind != 3 && lane < 4) {
      int q = lane & 1, b = lane >> 1;
      float x2 = sh.ns.p[0 + q][0][b];
      float x1 = sh.ns.p[2 + q][0][b];
      float vv = sh.ns.p[4 + q][0][b];
      int c = n * 64 + d0 + q;
      float t = x1 * vv;
      a.y[b * H + c] = (mix1L[c] * t + mix0L[b * H + c]) * x2;
    }
  }
  __syncthreads();
}

__device__ __forceinline__ void stageP_all(const MegaArgs& a, SH& sh, int wg, int nwg,
                                           int layer, int kind, const float* xin, const TP& tp0) {
  block_norm(xin, a.n1 + layer * H, sh);
  stageP_rb(a, sh, layer, kind, wg, tp0);
  for (int rb = wg + nwg; rb < 512; rb += nwg) {
    TP t = loadP(a, layer, kind, rb);
    stageP_rb(a, sh, layer, kind, rb, t);
  }
}

// ---------------------------------------------------------------------------
__device__ __forceinline__ void stageA_all(const MegaArgs& a, SH& sh, int wg, int nwg, int att) {
  int tid = threadIdx.x, lane = tid & 63;
  int pos = a.posp[0];
  int ck = (pos + 16) >> 4;
  const float* kcL = a.kc + (size_t)att * BATCH * SEQ * NHEADS * HDIM;
  const float* vcL = a.vc + (size_t)att * BATCH * SEQ * NHEADS * HDIM;
  for (int task = wg; task < 512; task += nwg) {
    int sp = task & 15, n = (task >> 4) & 15, b = task >> 8;
    int s0 = sp * ck;
    int send = min(s0 + ck, pos + 1);
    if (tid < 64) {
      int d = tid, jr = d & 31;
      float cs = a.cosT[pos * 32 + jr], sn = a.sinT[pos * 32 + jr];
      float qv = a.z[b * H3 + n * 64 + d];
      float qo = a.z[b * H3 + n * 64 + ((d + 32) & 63)];
      sh.att.q[d] = ((d < 32) ? (qv * cs - qo * sn) : (qv * cs + qo * sn)) * 0.125f;
      float kv = a.z[b * H3 + 1024 + n * 64 + d];
      float ko = a.z[b * H3 + 1024 + n * 64 + ((d + 32) & 63)];
      sh.att.k[d] = (d < 32) ? (kv * cs - ko * sn) : (kv * cs + ko * sn);
      sh.att.v[d] = a.z[b * H3 + 2048 + n * 64 + d];
    }
    __syncthreads();
    int slot = tid >> 2, quarter = tid & 3;
    int p = s0 + slot;
    float lg = -1e30f;
    if (p < send) {
      const float4* k4 = (p == pos) ? (const float4*)sh.att.k
                                    : (const float4*)(kcL + (((size_t)b * SEQ + p) * NHEADS + n) * HDIM);
      const float4* q4 = (const float4*)sh.att.q;
      float acc = 0.f;
#pragma unroll
      for (int jj = 0; jj < 4; jj++) {
        float4 kk = k4[quarter * 4 + jj], qq = q4[quarter * 4 + jj];
        acc += kk.x * qq.x + kk.y * qq.y + kk.z * qq.z + kk.w * qq.w;
      }
      acc += __shfl_xor(acc, 1, 64);
      acc += __shfl_xor(acc, 2, 64);
      lg = acc;
    }
    float mw = wredMax(lg);
    if (lane == 0) sh.att.red[tid >> 6] = mw;
    __syncthreads();
    float m = sh.att.red[0];
#pragma unroll
    for (int jj = 1; jj < 8; jj++) m = fmaxf(m, sh.att.red[jj]);
    float ee = expf(lg - m);
    if (quarter == 0) sh.att.e[slot] = ee;
    float ssum = wredSum(quarter == 0 ? ee : 0.f);
    __syncthreads();
    if (lane == 0) sh.att.red[tid >> 6] = ssum;
    __syncthreads();
    float lsum = 0.f;
#pragma unroll
    for (int jj = 0; jj < 8; jj++) lsum += sh.att.red[jj];
    int d = tid & 63, prow = tid >> 6;
    float acc2 = 0.f;
    for (int jj = prow; jj < ck; jj += 8) {
      int pp = s0 + jj;
      if (pp < send) {
        const float* vrow = (pp == pos) ? sh.att.v
                                        : (vcL + (((size_t)b * SEQ + pp) * NHEADS + n) * HDIM);
        acc2 += sh.att.e[jj] * vrow[d];
      }
    }
    sh.att.osum[prow][d] = acc2;
    __syncthreads();
    float* Pp = a.attP + (size_t)task * 66;
    if (tid < 64) {
      float o = 0.f;
#pragma unroll
      for (int jj = 0; jj < 8; jj++) o += sh.att.osum[jj][d];
      Pp[d] = o;
    } else if (tid == 64) Pp[64] = m;
    else if (tid == 65) Pp[65] = lsum;
    __syncthreads();
  }
}

// ---------------------------------------------------------------------------
__device__ __forceinline__ void stageOut_rb(const MegaArgs& a, SH& sh, int layer,
                                            int rb, const TO& to, const float* xin) {
  const float* ob = a.ob + layer * H;
  int tid = threadIdx.x, lane = tid & 63, wave = tid >> 6;
  int j = wave >> 2, ch = wave & 3;
  float4 ya = *(const float4*)&sh.o.ys[0][(ch << 8) + (lane << 2)];
  float4 yb = *(const float4*)&sh.o.ys[1][(ch << 8) + (lane << 2)];
  float p0 = to.w.x * ya.x + to.w.y * ya.y + to.w.z * ya.z + to.w.w * ya.w;
  float p1 = to.w.x * yb.x + to.w.y * yb.y + to.w.z * yb.z + to.w.w * yb.w;
  p0 = wredSum(p0); p1 = wredSum(p1);
  if (lane == 0) { sh.o.pr[j][ch][0] = p0; sh.o.pr[j][ch][1] = p1; }
  __syncthreads();
  if (wave == 0 && lane < 16) {
    int jj = lane >> 3, b = (lane >> 2) & 1, cc = lane & 3;
    float v = sh.o.pr[jj][cc][b];
    v += __shfl_xor(v, 1, 64);
    v += __shfl_xor(v, 2, 64);
    if (cc == 0) {
      int gr = rb * 2 + jj;
      a.xM[b * H + gr] = v + ob[gr] + xin[b * H + gr];
    }
  }
  __syncthreads();
}

__device__ __forceinline__ void stageOut_all(const MegaArgs& a, SH& sh, int wg, int nwg,
                                             int layer, int kind, const float* xin, const TO& to0) {
  int tid = threadIdx.x;
  if (kind != 3) {
    for (int e = tid; e < 2048; e += 512) (&sh.o.ys[0][0])[e] = a.y[e];
  } else {
    for (int e = tid; e < 2048; e += 512) {
      int b = e >> 10, c = e & 1023, n = c >> 6, d = c & 63;
      const float* P = a.attP + (size_t)((b * 16 + n) * 16) * 66;
      float M = -1e30f;
#pragma unroll
      for (int sp = 0; sp < 16; sp++) M = fmaxf(M, P[sp * 66 + 64]);
      float L = 0.f, num = 0.f;
#pragma unroll
      for (int sp = 0; sp < 16; sp++) {
        float w = expf(P[sp * 66 + 64] - M);
        L += w * P[sp * 66 + 65];
        num += w * P[sp * 66 + d];
      }
      (&sh.o.ys[0][0])[e] = num / L;
    }
  }
  __syncthreads();
  stageOut_rb(a, sh, layer, wg, to0, xin);
  for (int rb = wg + nwg; rb < 512; rb += nwg) {
    TO t = loadOut(a, layer, rb);
    stageOut_rb(a, sh, layer, rb, t, xin);
  }
}

// ---------------------------------------------------------------------------
__device__ __forceinline__ void stageW1_rb(const MegaArgs& a, SH& sh, int layer,
                                           int rb, const T1& t1) {
  int tid = threadIdx.x, lane = tid & 63, wave = tid >> 6;
  float part[2][2];
#pragma unroll
  for (int k = 0; k < 2; k++) {
    int ch = (wave + 8 * k) & 3;
    float4 xa = *(const float4*)&sh.ns.xe[0][(ch << 8) + (lane << 2)];
    float4 xb = *(const float4*)&sh.ns.xe[1][(ch << 8) + (lane << 2)];
    part[k][0] = t1.w[k].x * xa.x + t1.w[k].y * xa.y + t1.w[k].z * xa.z + t1.w[k].w * xa.w;
    part[k][1] = t1.w[k].x * xb.x + t1.w[k].y * xb.y + t1.w[k].z * xb.z + t1.w[k].w * xb.w;
  }
#pragma unroll
  for (int k = 0; k < 2; k++) {
    float s0 = wredSum(part[k][0]);
    float s1 = wredSum(part[k][1]);
    int tt = wave + 8 * k, j = tt >> 2, ch = tt & 3;
    if (lane == 0) { sh.ns.p[j][ch][0] = s0; sh.ns.p[j][ch][1] = s1; }
  }
  __syncthreads();
  if (wave == 0 && lane < 32) {
    int j = lane >> 3, b = (lane >> 2) & 1, ch = lane & 3;
    float v = sh.ns.p[j][ch][b];
    v += __shfl_xor(v, 1, 64);
    v += __shfl_xor(v, 2, 64);
    if (ch == 0) a.h[b * FF + rb * 4 + j] = gelu_t(v * sh.ns.scl[b]);
  }
  __syncthreads();
}

__device__ __forceinline__ void stageW1_all(const MegaArgs& a, SH& sh, int wg, int nwg,
                                            int layer, const T1& t10) {
  block_norm(a.xM, a.n2 + layer * H, sh);
  stageW1_rb(a, sh, layer, wg, t10);
  for (int rb = wg + nwg; rb < 512; rb += nwg) {
    T1 t = loadW1(a, layer, rb);
    stageW1_rb(a, sh, layer, rb, t);
  }
}

// ---------------------------------------------------------------------------
__device__ __forceinline__ void stageW2_rb(const MegaArgs& a, SH& sh, int layer,
                                           int rb, const T2& t2, float* xout) {
  int tid = threadIdx.x, lane = tid & 63, wave = tid >> 6;
  float part[2][2];
#pragma unroll
  for (int k = 0; k < 2; k++) {
    int ch = (wave + 8 * k) & 7;
    float4 ha = *(const float4*)&sh.w2.hs[0][(ch << 8) + (lane << 2)];
    float4 hb = *(const float4*)&sh.w2.hs[1][(ch << 8) + (lane << 2)];
    part[k][0] = t2.w[k].x * ha.x + t2.w[k].y * ha.y + t2.w[k].z * ha.z + t2.w[k].w * ha.w;
    part[k][1] = t2.w[k].x * hb.x + t2.w[k].y * hb.y + t2.w[k].z * hb.z + t2.w[k].w * hb.w;
  }
#pragma unroll
  for (int k = 0; k < 2; k++) {
    float s0 = wredSum(part[k][0]);
    float s1 = wredSum(part[k][1]);
    int tt = wave + 8 * k, j = tt >> 3, ch = tt & 7;
    if (lane == 0) { sh.w2.pr[j][ch][0] = s0; sh.w2.pr[j][ch][1] = s1; }
  }
  __syncthreads();
  if (wave == 0 && lane < 32) {
    int j = lane >> 4, b = (lane >> 3) & 1, ch = lane & 7;
    float v = sh.w2.pr[j][ch][b];
    v += __shfl_xor(v, 1, 64);
    v += __shfl_xor(v, 2, 64);
    v += __shfl_xor(v, 4, 64);
    if (ch == 0) {
      int gr = rb * 2 + j;
      xout[b * H + gr] = v + a.xM[b * H + gr];
    }
  }
  __syncthreads();
}

__device__ __forceinline__ void stageW2_all(const MegaArgs& a, SH& sh, int wg, int nwg,
                                            int layer, const T2& t20, float* xout) {
  int tid = threadIdx.x;
  for (int e = tid; e < 4096; e += 512) (&sh.w2.hs[0][0])[e] = a.h[e];
  __syncthreads();
  stageW2_rb(a, sh, layer, wg, t20, xout);
  for (int rb = wg + nwg; rb < 512; rb += nwg) {
    T2 t = loadW2(a, layer, rb);
    stageW2_rb(a, sh, layer, rb, t, xout);
  }
}

// ---------------------------------------------------------------------------
__global__ __launch_bounds__(512, 4) void mega(MegaArgs a) {
  __shared__ SH sh;
  int wg = blockIdx.x, nwg = gridDim.x;
  int st = 0, att = 0;
  const float* xin = a.x0;
  TP tp = loadP(a, 0, d_KIND[0], wg);
  for (int i = 0; i < LAYERS; i++) {
    int kind = d_KIND[i];
    stageP_all(a, sh, wg, nwg, i, kind, xin, tp);
    TO to = loadOut(a, i, wg);                       // prefetch across barrier
    gridbar(a.bar, st++, wg, nwg);
    if (kind == 3) {
      stageA_all(a, sh, wg, nwg, att);
      gridbar(a.bar, st++, wg, nwg);
      att++;
    }
    stageOut_all(a, sh, wg, nwg, i, kind, xin, to);
    T1 t1 = loadW1(a, i, wg);                        // prefetch
    gridbar(a.bar, st++, wg, nwg);
    stageW1_all(a, sh, wg, nwg, i, t1);
    T2 t2 = loadW2(a, i, wg);                        // prefetch
    gridbar(a.bar, st++, wg, nwg);
    float* xout = (i == LAYERS - 1) ? a.out : ((i & 1) ? a.xB : a.xA);
    stageW2_all(a, sh, wg, nwg, i, t2, xout);
    if (i != LAYERS - 1) {
      tp = loadP(a, i + 1, d_KIND[i + 1], wg);       // prefetch next layer
      gridbar(a.bar, st++, wg, nwg);
    }
    xin = xout;
  }
}

// ---------------------------------------------------------------------------
// prep: hoist state-linear terms + zero barrier area
// ---------------------------------------------------------------------------
__global__ __launch_bounds__(256) void prep_kernel(
    const float* __restrict__ sf_w, const float* __restrict__ sf_b,
    const float* __restrict__ fir_state,
    const float* __restrict__ hcs_h, const float* __restrict__ hcs_D, const float* __restrict__ hcs_state,
    const float* __restrict__ hcm_h, const float* __restrict__ hcm_D, const float* __restrict__ hcm_state,
    const float* __restrict__ lp, const float* __restrict__ resd, const float* __restrict__ hcl_D,
    const float* __restrict__ iir,
    unsigned long long kbits,
    float* __restrict__ sfd, float* __restrict__ sfc,
    float* __restrict__ mix0, float* __restrict__ mix1, int* __restrict__ bar)
{
  int blk = blockIdx.x, tid = threadIdx.x;
  if (blk < 768) {
    int idx = blk * 256 + tid;
    int i = idx / (BATCH * H3);
    int r = idx % (BATCH * H3);
    int b = r / H3, ch = r % H3;
    const float* fs = fir_state + ((size_t)(i * BATCH + b) * H3 + ch) * 2;
    const float* sw = sf_w + ((size_t)i * H3 + ch) * 3;
    sfd[idx] = fs[0] * sw[0] + fs[1] * sw[1] + sf_b[i * H3 + ch];
    if (b == 0) sfc[i * H3 + ch] = sw[2];
  } else if (blk < 1024) {
    int idx = (blk - 768) * 256 + tid;
    int i = idx >> 11;
    int r = idx & 2047;
    int b = r >> 10, c = r & 1023;
    int kind = (int)((kbits >> (2 * i)) & 3ull);
    if (kind == 0) {
      const float* st = hcs_state + ((size_t)(i * BATCH + b) * H + c) * 6;
      const float* hh = hcs_h + ((size_t)i * H + c) * 7;
      float acc = 0.f;
#pragma unroll
      for (int k = 0; k < 6; k++) acc += st[k] * hh[k];
      mix0[idx] = acc + hcs_D[i * H + c];
      if (b == 0) mix1[i * H + c] = hh[6];
    } else if (kind == 2) {
      const float* ii = iir + ((size_t)(i * BATCH + b) * H + c) * 16;
      const float* lpp = lp + ((size_t)i * H + c) * 16;
      const float* rs = resd + ((size_t)i * H + c) * 16;
      float acc = 0.f, rsum = 0.f;
#pragma unroll
      for (int k = 0; k < 16; k++) { float rv = rs[k]; acc += rv * expf(lpp[k]) * ii[k]; rsum += rv; }
      mix0[idx] = acc;
      if (b == 0) mix1[i * H + c] = rsum + hcl_D[i * H + c];
    }
  } else if (blk < 5632) {
    int w = tid >> 6, lane = tid & 63;
    int widx = (blk - 1024) * 4 + w;
    if (widx < 9 * BATCH * H) {
      int li = widx >> 11;
      int r = widx & 2047;
      int b = r >> 10, c = r & 1023;
      int i = (li >> 1) * 7 + ((li & 1) ? 5 : 1);
      const float* st = hcm_state + ((size_t)(i * BATCH + b) * H + c) * 127;
      const float* hh = hcm_h + ((size_t)i * H + c) * 128;
      float acc = 0.f;
      int k = lane;
      if (k < 127) acc += st[k] * hh[127 - k];
      k = lane + 64;
      if (k < 127) acc += st[k] * hh[127 - k];
      acc = wredSum(acc);
      if (lane == 0) {
        mix0[(i * BATCH + b) * H + c] = acc;
        if (b == 0) mix1[i * H + c] = hh[0] + hcm_D[i * H + c];
      }
    }
  } else {
    int idx = (blk - 5632) * 256 + tid;
    if (idx < CNT_INTS + FLG_INTS) bar[idx] = 0;
  }
}

// ---------------------------------------------------------------------------
extern "C" void kernel_launch(void* const* d_in, const int* in_sizes, int n_in,
                              void* d_out, int out_size, void* d_ws, size_t ws_size,
                              hipStream_t stream) {
  (void)in_sizes; (void)n_in; (void)out_size; (void)ws_size;
  const float* x0    = (const float*)d_in[0];
  const int*   posp  = (const int*)d_in[1];
  const float* n1    = (const float*)d_in[2];
  const float* n2    = (const float*)d_in[3];
  const float* pW    = (const float*)d_in[4];
  const float* pb    = (const float*)d_in[5];
  const float* oW    = (const float*)d_in[6];
  const float* ob    = (const float*)d_in[7];
  const float* W1    = (const float*)d_in[8];
  const float* W2    = (const float*)d_in[9];
  const float* sfw   = (const float*)d_in[10];
  const float* sfb   = (const float*)d_in[11];
  const float* hcs_h = (const float*)d_in[12];
  const float* hcs_D = (const float*)d_in[13];
  const float* hcm_h = (const float*)d_in[14];
  const float* hcm_D = (const float*)d_in[15];
  const float* lp    = (const float*)d_in[16];
  const float* resd  = (const float*)d_in[17];
  const float* hclD  = (const float*)d_in[18];
  const float* fir   = (const float*)d_in[19];
  const float* hcsS  = (const float*)d_in[20];
  const float* hcmS  = (const float*)d_in[21];
  const float* iir   = (const float*)d_in[22];
  const float* kc    = (const float*)d_in[23];
  const float* vc    = (const float*)d_in[24];
  const float* cosT  = (const float*)d_in[25];
  const float* sinT  = (const float*)d_in[26];

  float* ws   = (float*)d_ws;
  float* xA   = ws;                  // 2048
  float* xB   = ws + 2048;           // 2048
  float* xM   = ws + 4096;           // 2048
  float* zb   = ws + 6144;           // 6144
  float* yb   = ws + 12288;          // 2048
  float* hb   = ws + 14336;          // 4096
  float* attP = ws + 18432;          // 33792
  float* sfd  = ws + 52224;          // 196608
  float* sfc  = ws + 248832;         // 98304
  float* mix0 = ws + 347136;         // 65536
  float* mix1 = ws + 412672;         // 32768
  int*   bar  = (int*)(ws + 445440); // CNT_INTS + FLG_INTS = 184320 ints

  static const int KIND[LAYERS] = {0,1,2,3,0,1,2,0,1,2,3,0,1,2,0,1,2,3,0,1,2,0,1,2,3,0,1,2,0,1,2,3};
  unsigned long long kbits = 0ull;
  for (int i = 0; i < LAYERS; i++) kbits |= ((unsigned long long)KIND[i]) << (2 * i);

  int zblocks = (CNT_INTS + FLG_INTS + 255) / 256;  // 720
  prep_kernel<<<5632 + zblocks, 256, 0, stream>>>(sfw, sfb, fir, hcs_h, hcs_D, hcsS,
      hcm_h, hcm_D, hcmS, lp, resd, hclD, iir, kbits, sfd, sfc, mix0, mix1, bar);

  int occ = 0;
  hipError_t oe = hipOccupancyMaxActiveBlocksPerMultiprocessor(&occ, mega, 512, 0);
  if (oe != hipSuccess || occ < 1) occ = 1;
  int nwg = occ * 256;
  if (nwg > 512) nwg = 512;

  MegaArgs ma;
  ma.x0 = x0; ma.posp = posp; ma.n1 = n1; ma.n2 = n2;
  ma.pW = pW; ma.pb = pb; ma.oW = oW; ma.ob = ob; ma.W1 = W1; ma.W2 = W2;
  ma.sfc = sfc; ma.sfd = sfd; ma.mix0 = mix0; ma.mix1 = mix1;
  ma.kc = kc; ma.vc = vc; ma.cosT = cosT; ma.sinT = sinT;
  ma.z = zb; ma.y = yb; ma.xA = xA; ma.xB = xB; ma.xM = xM; ma.h = hb; ma.attP = attP;
  ma.bar = bar; ma.out = (float*)d_out; ma.nwg = nwg;

  void* kp[] = { &ma };
  hipLaunchCooperativeKernel(mega, dim3(nwg), dim3(512), kp, 0, stream);
}

// Round 4
// 2692.761 us; speedup vs baseline: 1.0003x; 1.0003x over previous
//
#include <hip/hip_runtime.h>
#include <hip/hip_bf16.h>
#include <math.h>

#define LAYERS 32
#define H      1024
#define H3     3072
#define NHEADS 16
#define HDIM   64
#define FF     2048
#define BATCH  2
#define SEQ    2048
#define EPSF   1e-6f
#define NSLOT  512
#define BAR_INTS (NSLOT * 16 + 8 * 16)

__constant__ int d_KIND[LAYERS] = {0,1,2,3,0,1,2,0,1,2,3,0,1,2,0,1,2,3,0,1,2,0,1,2,3,0,1,2,0,1,2,3};

__device__ __forceinline__ float wredSum(float v) {
#pragma unroll
  for (int m = 32; m >= 1; m >>= 1) v += __shfl_xor(v, m, 64);
  return v;
}
__device__ __forceinline__ float wredMax(float v) {
#pragma unroll
  for (int m = 32; m >= 1; m >>= 1) v = fmaxf(v, __shfl_xor(v, m, 64));
  return v;
}
__device__ __forceinline__ float gelu_t(float x) {
  return 0.5f * x * (1.0f + tanhf(0.7978845608028654f * (x + 0.044715f * x * x * x)));
}

struct NS   { float xe[2][1024]; float red[16]; float scl[2]; float p[6][4][2]; };
struct W2S  { float hs[2][2048]; float pr[2][8][2]; };
struct OUTS { float ys[2][1024]; float pr[2][4][2]; };
struct ATTS { float q[64]; float k[64]; float v[64]; float e[128]; float red[16]; float osum[8][64]; };
union SH { NS ns; W2S w2; OUTS o; ATTS att; };

struct MegaArgs {
  const float* x0; const int* posp;
  const float* n1; const float* n2;
  const float* pW; const float* pb; const float* oW; const float* ob;
  const float* W1; const float* W2;
  const float* sfc; const float* sfd; const float* mix0; const float* mix1;
  const float* kc; const float* vc; const float* cosT; const float* sinT;
  float* z; float* y; float* xA; float* xB; float* xM; float* h; float* attP;
  int* bar; float* out; int nwg;
};

// ---------------------------------------------------------------------------
// grid barrier, contention-free arrival:
//  - each WG owns a private cacheline slot; arrival = release STORE of the
//    monotonic stage number (no RMW, no line sharing, all arrivals parallel)
//  - leader WG0: thread t watches slot t until it reaches the stage value
//  - release: 8 replicated flag lines store the stage number; spinners poll
//    flag[wg&7] with s_sleep backoff. Monotonic values => no reset, no reuse
//    races; prep zeroes the array once per call.
// ---------------------------------------------------------------------------
__device__ __forceinline__ void gridbar(int* bar, int stage, int wg, int nwg) {
  __syncthreads();
  int tid = threadIdx.x;
  int* slots = bar;
  int* flags = bar + NSLOT * 16;
  if (tid == 0)
    __hip_atomic_store(&slots[wg * 16], stage, __ATOMIC_RELEASE, __HIP_MEMORY_SCOPE_AGENT);
  if (wg == 0) {
    if (tid < nwg) {
      while (__hip_atomic_load(&slots[tid * 16], __ATOMIC_RELAXED, __HIP_MEMORY_SCOPE_AGENT) < stage)
        __builtin_amdgcn_s_sleep(1);
    }
    __syncthreads();
    if (tid < 8) {
      __builtin_amdgcn_fence(__ATOMIC_ACQUIRE, "agent");
      __hip_atomic_store(&flags[tid * 16], stage, __ATOMIC_RELEASE, __HIP_MEMORY_SCOPE_AGENT);
    }
  } else {
    if (tid == 0) {
      while (__hip_atomic_load(&flags[(wg & 7) * 16], __ATOMIC_RELAXED, __HIP_MEMORY_SCOPE_AGENT) < stage)
        __builtin_amdgcn_s_sleep(2);
      __builtin_amdgcn_fence(__ATOMIC_ACQUIRE, "agent");
    }
  }
  __syncthreads();
}

// ---------------------------------------------------------------------------
// register weight tiles + loaders (addresses static per (stage, rb))
// ---------------------------------------------------------------------------
struct TP { float4 w[3]; };
struct TO { float4 w; };
struct T1 { float4 w[2]; };
struct T2 { float4 w[2]; };

__device__ __forceinline__ TP loadP(const MegaArgs& a, int layer, int kind, int rb) {
  int tid = threadIdx.x, lane = tid & 63, wave = tid >> 6;
  const float* W = a.pW + (size_t)layer * H3 * H;
  int n = rb >> 5, d0 = (rb & 31) << 1;
  TP t;
#pragma unroll
  for (int k = 0; k < 3; k++) {
    int tt = wave + 8 * k, j = tt >> 2, ch = tt & 3;
    int grow = (kind == 3) ? (rb * 6 + j) : (n * 192 + (j >> 1) * 64 + d0 + (j & 1));
    t.w[k] = *(const float4*)(W + (size_t)grow * H + (ch << 8) + (lane << 2));
  }
  return t;
}
__device__ __forceinline__ TO loadOut(const MegaArgs& a, int layer, int rb) {
  int tid = threadIdx.x, lane = tid & 63, wave = tid >> 6;
  const float* W = a.oW + (size_t)layer * H * H;
  int j = wave >> 2, ch = wave & 3;
  TO t;
  t.w = *(const float4*)(W + (size_t)(rb * 2 + j) * H + (ch << 8) + (lane << 2));
  return t;
}
__device__ __forceinline__ T1 loadW1(const MegaArgs& a, int layer, int rb) {
  int tid = threadIdx.x, lane = tid & 63, wave = tid >> 6;
  const float* W = a.W1 + (size_t)layer * FF * H;
  T1 t;
#pragma unroll
  for (int k = 0; k < 2; k++) {
    int tt = wave + 8 * k, j = tt >> 2, ch = tt & 3;
    t.w[k] = *(const float4*)(W + (size_t)(rb * 4 + j) * H + (ch << 8) + (lane << 2));
  }
  return t;
}
__device__ __forceinline__ T2 loadW2(const MegaArgs& a, int layer, int rb) {
  int tid = threadIdx.x, lane = tid & 63, wave = tid >> 6;
  const float* W = a.W2 + (size_t)layer * H * FF;
  T2 t;
#pragma unroll
  for (int k = 0; k < 2; k++) {
    int tt = wave + 8 * k, j = tt >> 3, ch = tt & 7;
    t.w[k] = *(const float4*)(W + (size_t)(rb * 2 + j) * FF + (ch << 8) + (lane << 2));
  }
  return t;
}

// ---------------------------------------------------------------------------
__device__ __forceinline__ void block_norm(const float* __restrict__ xin,
                                           const float* __restrict__ nw, SH& sh) {
  int tid = threadIdx.x, lane = tid & 63, wave = tid >> 6;
  float4 xv = ((const float4*)xin)[tid];
  int b = tid >> 8, ci = tid & 255;
  float4 nv = ((const float4*)nw)[ci];
  float ss = xv.x * xv.x + xv.y * xv.y + xv.z * xv.z + xv.w * xv.w;
  ((float4*)&sh.ns.xe[b][ci << 2])[0] =
      make_float4(xv.x * nv.x, xv.y * nv.y, xv.z * nv.z, xv.w * nv.w);
  ss = wredSum(ss);
  if (lane == 0) sh.ns.red[wave] = ss;
  __syncthreads();
  if (threadIdx.x == 0) {
    sh.ns.scl[0] = rsqrtf((sh.ns.red[0] + sh.ns.red[1] + sh.ns.red[2] + sh.ns.red[3]) * (1.0f / 1024.f) + EPSF);
    sh.ns.scl[1] = rsqrtf((sh.ns.red[4] + sh.ns.red[5] + sh.ns.red[6] + sh.ns.red[7]) * (1.0f / 1024.f) + EPSF);
  }
  __syncthreads();
}

// ---------------------------------------------------------------------------
__device__ __forceinline__ void stageP_rb(const MegaArgs& a, SH& sh, int layer,
                                          int kind, int rb, const TP& tp) {
  const float* pb = a.pb + layer * H3;
  const float* sfcL = a.sfc + (size_t)layer * H3;
  const float* sfdL = a.sfd + (size_t)layer * 2 * H3;
  const float* mix0L = a.mix0 + (size_t)layer * 2 * H;
  const float* mix1L = a.mix1 + (size_t)layer * H;
  int tid = threadIdx.x, lane = tid & 63, wave = tid >> 6;
  int n = rb >> 5, d0 = (rb & 31) << 1;
  float part[3][2];
#pragma unroll
  for (int k = 0; k < 3; k++) {
    int ch = (wave + 8 * k) & 3;
    float4 xa = *(const float4*)&sh.ns.xe[0][(ch << 8) + (lane << 2)];
    float4 xb = *(const float4*)&sh.ns.xe[1][(ch << 8) + (lane << 2)];
    part[k][0] = tp.w[k].x * xa.x + tp.w[k].y * xa.y + tp.w[k].z * xa.z + tp.w[k].w * xa.w;
    part[k][1] = tp.w[k].x * xb.x + tp.w[k].y * xb.y + tp.w[k].z * xb.z + tp.w[k].w * xb.w;
  }
#pragma unroll
  for (int k = 0; k < 3; k++) {
    float s0 = wredSum(part[k][0]);
    float s1 = wredSum(part[k][1]);
    int tt = wave + 8 * k, j = tt >> 2, ch = tt & 3;
    if (lane == 0) { sh.ns.p[j][ch][0] = s0; sh.ns.p[j][ch][1] = s1; }
  }
  __syncthreads();
  if (wave == 0) {
    if (lane < 48) {
      int j = lane >> 3, b = (lane >> 2) & 1, ch = lane & 3;
      float v = sh.ns.p[j][ch][b];
      v += __shfl_xor(v, 1, 64);
      v += __shfl_xor(v, 2, 64);
      if (ch == 0) {
        int grow = (kind == 3) ? (rb * 6 + j) : (n * 192 + (j >> 1) * 64 + d0 + (j & 1));
        float zraw = v * sh.ns.scl[b] + pb[grow];
        if (kind == 3) {
          a.z[b * H3 + grow] = zraw;
        } else {
          sh.ns.p[j][0][b] = sfcL[grow] * zraw + sfdL[b * H3 + grow];
        }
      }
    }
    if (kind != 3 && lane < 4) {
      int q = lane & 1, b = lane >> 1;
      float x2 = sh.ns.p[0 + q][0][b];
      float x1 = sh.ns.p[2 + q][0][b];
      float vv = sh.ns.p[4 + q][0][b];
      int c = n * 64 + d0 + q;
      float t = x1 * vv;
      a.y[b * H + c] = (mix1L[c] * t + mix0L[b * H + c]) * x2;
    }
  }
  __syncthreads();
}

__device__ __forceinline__ void stageP_all(const MegaArgs& a, SH& sh, int wg, int nwg,
                                           int layer, int kind, const float* xin, const TP& tp0) {
  block_norm(xin, a.n1 + layer * H, sh);
  stageP_rb(a, sh, layer, kind, wg, tp0);
  for (int rb = wg + nwg; rb < 512; rb += nwg) {
    TP t = loadP(a, layer, kind, rb);
    stageP_rb(a, sh, layer, kind, rb, t);
  }
}

// ---------------------------------------------------------------------------
__device__ __forceinline__ void stageA_all(const MegaArgs& a, SH& sh, int wg, int nwg, int att) {
  int tid = threadIdx.x, lane = tid & 63;
  int pos = a.posp[0];
  int ck = (pos + 16) >> 4;
  const float* kcL = a.kc + (size_t)att * BATCH * SEQ * NHEADS * HDIM;
  const float* vcL = a.vc + (size_t)att * BATCH * SEQ * NHEADS * HDIM;
  for (int task = wg; task < 512; task += nwg) {
    int sp = task & 15, n = (task >> 4) & 15, b = task >> 8;
    int s0 = sp * ck;
    int send = min(s0 + ck, pos + 1);
    if (tid < 64) {
      int d = tid, jr = d & 31;
      float cs = a.cosT[pos * 32 + jr], sn = a.sinT[pos * 32 + jr];
      float qv = a.z[b * H3 + n * 64 + d];
      float qo = a.z[b * H3 + n * 64 + ((d + 32) & 63)];
      sh.att.q[d] = ((d < 32) ? (qv * cs - qo * sn) : (qv * cs + qo * sn)) * 0.125f;
      float kv = a.z[b * H3 + 1024 + n * 64 + d];
      float ko = a.z[b * H3 + 1024 + n * 64 + ((d + 32) & 63)];
      sh.att.k[d] = (d < 32) ? (kv * cs - ko * sn) : (kv * cs + ko * sn);
      sh.att.v[d] = a.z[b * H3 + 2048 + n * 64 + d];
    }
    __syncthreads();
    int slot = tid >> 2, quarter = tid & 3;
    int p = s0 + slot;
    float lg = -1e30f;
    if (p < send) {
      const float4* k4 = (p == pos) ? (const float4*)sh.att.k
                                    : (const float4*)(kcL + (((size_t)b * SEQ + p) * NHEADS + n) * HDIM);
      const float4* q4 = (const float4*)sh.att.q;
      float acc = 0.f;
#pragma unroll
      for (int jj = 0; jj < 4; jj++) {
        float4 kk = k4[quarter * 4 + jj], qq = q4[quarter * 4 + jj];
        acc += kk.x * qq.x + kk.y * qq.y + kk.z * qq.z + kk.w * qq.w;
      }
      acc += __shfl_xor(acc, 1, 64);
      acc += __shfl_xor(acc, 2, 64);
      lg = acc;
    }
    float mw = wredMax(lg);
    if (lane == 0) sh.att.red[tid >> 6] = mw;
    __syncthreads();
    float m = sh.att.red[0];
#pragma unroll
    for (int jj = 1; jj < 8; jj++) m = fmaxf(m, sh.att.red[jj]);
    float ee = expf(lg - m);
    if (quarter == 0) sh.att.e[slot] = ee;
    float ssum = wredSum(quarter == 0 ? ee : 0.f);
    __syncthreads();
    if (lane == 0) sh.att.red[tid >> 6] = ssum;
    __syncthreads();
    float lsum = 0.f;
#pragma unroll
    for (int jj = 0; jj < 8; jj++) lsum += sh.att.red[jj];
    int d = tid & 63, prow = tid >> 6;
    float acc2 = 0.f;
    for (int jj = prow; jj < ck; jj += 8) {
      int pp = s0 + jj;
      if (pp < send) {
        const float* vrow = (pp == pos) ? sh.att.v
                                        : (vcL + (((size_t)b * SEQ + pp) * NHEADS + n) * HDIM);
        acc2 += sh.att.e[jj] * vrow[d];
      }
    }
    sh.att.osum[prow][d] = acc2;
    __syncthreads();
    float* Pp = a.attP + (size_t)task * 66;
    if (tid < 64) {
      float o = 0.f;
#pragma unroll
      for (int jj = 0; jj < 8; jj++) o += sh.att.osum[jj][d];
      Pp[d] = o;
    } else if (tid == 64) Pp[64] = m;
    else if (tid == 65) Pp[65] = lsum;
    __syncthreads();
  }
}

// ---------------------------------------------------------------------------
__device__ __forceinline__ void stageOut_rb(const MegaArgs& a, SH& sh, int layer,
                                            int rb, const TO& to, const float* xin) {
  const float* ob = a.ob + layer * H;
  int tid = threadIdx.x, lane = tid & 63, wave = tid >> 6;
  int j = wave >> 2, ch = wave & 3;
  float4 ya = *(const float4*)&sh.o.ys[0][(ch << 8) + (lane << 2)];
  float4 yb = *(const float4*)&sh.o.ys[1][(ch << 8) + (lane << 2)];
  float p0 = to.w.x * ya.x + to.w.y * ya.y + to.w.z * ya.z + to.w.w * ya.w;
  float p1 = to.w.x * yb.x + to.w.y * yb.y + to.w.z * yb.z + to.w.w * yb.w;
  p0 = wredSum(p0); p1 = wredSum(p1);
  if (lane == 0) { sh.o.pr[j][ch][0] = p0; sh.o.pr[j][ch][1] = p1; }
  __syncthreads();
  if (wave == 0 && lane < 16) {
    int jj = lane >> 3, b = (lane >> 2) & 1, cc = lane & 3;
    float v = sh.o.pr[jj][cc][b];
    v += __shfl_xor(v, 1, 64);
    v += __shfl_xor(v, 2, 64);
    if (cc == 0) {
      int gr = rb * 2 + jj;
      a.xM[b * H + gr] = v + ob[gr] + xin[b * H + gr];
    }
  }
  __syncthreads();
}

__device__ __forceinline__ void stageOut_all(const MegaArgs& a, SH& sh, int wg, int nwg,
                                             int layer, int kind, const float* xin, const TO& to0) {
  int tid = threadIdx.x;
  if (kind != 3) {
    for (int e = tid; e < 2048; e += 512) (&sh.o.ys[0][0])[e] = a.y[e];
  } else {
    for (int e = tid; e < 2048; e += 512) {
      int b = e >> 10, c = e & 1023, n = c >> 6, d = c & 63;
      const float* P = a.attP + (size_t)((b * 16 + n) * 16) * 66;
      float M = -1e30f;
#pragma unroll
      for (int sp = 0; sp < 16; sp++) M = fmaxf(M, P[sp * 66 + 64]);
      float L = 0.f, num = 0.f;
#pragma unroll
      for (int sp = 0; sp < 16; sp++) {
        float w = expf(P[sp * 66 + 64] - M);
        L += w * P[sp * 66 + 65];
        num += w * P[sp * 66 + d];
      }
      (&sh.o.ys[0][0])[e] = num / L;
    }
  }
  __syncthreads();
  stageOut_rb(a, sh, layer, wg, to0, xin);
  for (int rb = wg + nwg; rb < 512; rb += nwg) {
    TO t = loadOut(a, layer, rb);
    stageOut_rb(a, sh, layer, rb, t, xin);
  }
}

// ---------------------------------------------------------------------------
__device__ __forceinline__ void stageW1_rb(const MegaArgs& a, SH& sh, int layer,
                                           int rb, const T1& t1) {
  int tid = threadIdx.x, lane = tid & 63, wave = tid >> 6;
  float part[2][2];
#pragma unroll
  for (int k = 0; k < 2; k++) {
    int ch = (wave + 8 * k) & 3;
    float4 xa = *(const float4*)&sh.ns.xe[0][(ch << 8) + (lane << 2)];
    float4 xb = *(const float4*)&sh.ns.xe[1][(ch << 8) + (lane << 2)];
    part[k][0] = t1.w[k].x * xa.x + t1.w[k].y * xa.y + t1.w[k].z * xa.z + t1.w[k].w * xa.w;
    part[k][1] = t1.w[k].x * xb.x + t1.w[k].y * xb.y + t1.w[k].z * xb.z + t1.w[k].w * xb.w;
  }
#pragma unroll
  for (int k = 0; k < 2; k++) {
    float s0 = wredSum(part[k][0]);
    float s1 = wredSum(part[k][1]);
    int tt = wave + 8 * k, j = tt >> 2, ch = tt & 3;
    if (lane == 0) { sh.ns.p[j][ch][0] = s0; sh.ns.p[j][ch][1] = s1; }
  }
  __syncthreads();
  if (wave == 0 && lane < 32) {
    int j = lane >> 3, b = (lane >> 2) & 1, ch = lane & 3;
    float v = sh.ns.p[j][ch][b];
    v += __shfl_xor(v, 1, 64);
    v += __shfl_xor(v, 2, 64);
    if (ch == 0) a.h[b * FF + rb * 4 + j] = gelu_t(v * sh.ns.scl[b]);
  }
  __syncthreads();
}

__device__ __forceinline__ void stageW1_all(const MegaArgs& a, SH& sh, int wg, int nwg,
                                            int layer, const T1& t10) {
  block_norm(a.xM, a.n2 + layer * H, sh);
  stageW1_rb(a, sh, layer, wg, t10);
  for (int rb = wg + nwg; rb < 512; rb += nwg) {
    T1 t = loadW1(a, layer, rb);
    stageW1_rb(a, sh, layer, rb, t);
  }
}

// ---------------------------------------------------------------------------
__device__ __forceinline__ void stageW2_rb(const MegaArgs& a, SH& sh, int layer,
                                           int rb, const T2& t2, float* xout) {
  int tid = threadIdx.x, lane = tid & 63, wave = tid >> 6;
  float part[2][2];
#pragma unroll
  for (int k = 0; k < 2; k++) {
    int ch = (wave + 8 * k) & 7;
    float4 ha = *(const float4*)&sh.w2.hs[0][(ch << 8) + (lane << 2)];
    float4 hb = *(const float4*)&sh.w2.hs[1][(ch << 8) + (lane << 2)];
    part[k][0] = t2.w[k].x * ha.x + t2.w[k].y * ha.y + t2.w[k].z * ha.z + t2.w[k].w * ha.w;
    part[k][1] = t2.w[k].x * hb.x + t2.w[k].y * hb.y + t2.w[k].z * hb.z + t2.w[k].w * hb.w;
  }
#pragma unroll
  for (int k = 0; k < 2; k++) {
    float s0 = wredSum(part[k][0]);
    float s1 = wredSum(part[k][1]);
    int tt = wave + 8 * k, j = tt >> 3, ch = tt & 7;
    if (lane == 0) { sh.w2.pr[j][ch][0] = s0; sh.w2.pr[j][ch][1] = s1; }
  }
  __syncthreads();
  if (wave == 0 && lane < 32) {
    int j = lane >> 4, b = (lane >> 3) & 1, ch = lane & 7;
    float v = sh.w2.pr[j][ch][b];
    v += __shfl_xor(v, 1, 64);
    v += __shfl_xor(v, 2, 64);
    v += __shfl_xor(v, 4, 64);
    if (ch == 0) {
      int gr = rb * 2 + j;
      xout[b * H + gr] = v + a.xM[b * H + gr];
    }
  }
  __syncthreads();
}

__device__ __forceinline__ void stageW2_all(const MegaArgs& a, SH& sh, int wg, int nwg,
                                            int layer, const T2& t20, float* xout) {
  int tid = threadIdx.x;
  for (int e = tid; e < 4096; e += 512) (&sh.w2.hs[0][0])[e] = a.h[e];
  __syncthreads();
  stageW2_rb(a, sh, layer, wg, t20, xout);
  for (int rb = wg + nwg; rb < 512; rb += nwg) {
    T2 t = loadW2(a, layer, rb);
    stageW2_rb(a, sh, layer, rb, t, xout);
  }
}

// ---------------------------------------------------------------------------
__global__ __launch_bounds__(512, 4) void mega(MegaArgs a) {
  __shared__ SH sh;
  int wg = blockIdx.x, nwg = gridDim.x;
  int st = 1, att = 0;
  const float* xin = a.x0;
  TP tp = loadP(a, 0, d_KIND[0], wg);
  for (int i = 0; i < LAYERS; i++) {
    int kind = d_KIND[i];
    stageP_all(a, sh, wg, nwg, i, kind, xin, tp);
    TO to = loadOut(a, i, wg);                       // prefetch across barrier
    gridbar(a.bar, st++, wg, nwg);
    if (kind == 3) {
      stageA_all(a, sh, wg, nwg, att);
      gridbar(a.bar, st++, wg, nwg);
      att++;
    }
    stageOut_all(a, sh, wg, nwg, i, kind, xin, to);
    T1 t1 = loadW1(a, i, wg);                        // prefetch
    gridbar(a.bar, st++, wg, nwg);
    stageW1_all(a, sh, wg, nwg, i, t1);
    T2 t2 = loadW2(a, i, wg);                        // prefetch
    gridbar(a.bar, st++, wg, nwg);
    float* xout = (i == LAYERS - 1) ? a.out : ((i & 1) ? a.xB : a.xA);
    stageW2_all(a, sh, wg, nwg, i, t2, xout);
    if (i != LAYERS - 1) {
      tp = loadP(a, i + 1, d_KIND[i + 1], wg);       // prefetch next layer
      gridbar(a.bar, st++, wg, nwg);
    }
    xin = xout;
  }
}

// ---------------------------------------------------------------------------
// prep: hoist state-linear terms + zero barrier area
// ---------------------------------------------------------------------------
__global__ __launch_bounds__(256) void prep_kernel(
    const float* __restrict__ sf_w, const float* __restrict__ sf_b,
    const float* __restrict__ fir_state,
    const float* __restrict__ hcs_h, const float* __restrict__ hcs_D, const float* __restrict__ hcs_state,
    const float* __restrict__ hcm_h, const float* __restrict__ hcm_D, const float* __restrict__ hcm_state,
    const float* __restrict__ lp, const float* __restrict__ resd, const float* __restrict__ hcl_D,
    const float* __restrict__ iir,
    unsigned long long kbits,
    float* __restrict__ sfd, float* __restrict__ sfc,
    float* __restrict__ mix0, float* __restrict__ mix1, int* __restrict__ bar)
{
  int blk = blockIdx.x, tid = threadIdx.x;
  if (blk < 768) {
    int idx = blk * 256 + tid;
    int i = idx / (BATCH * H3);
    int r = idx % (BATCH * H3);
    int b = r / H3, ch = r % H3;
    const float* fs = fir_state + ((size_t)(i * BATCH + b) * H3 + ch) * 2;
    const float* sw = sf_w + ((size_t)i * H3 + ch) * 3;
    sfd[idx] = fs[0] * sw[0] + fs[1] * sw[1] + sf_b[i * H3 + ch];
    if (b == 0) sfc[i * H3 + ch] = sw[2];
  } else if (blk < 1024) {
    int idx = (blk - 768) * 256 + tid;
    int i = idx >> 11;
    int r = idx & 2047;
    int b = r >> 10, c = r & 1023;
    int kind = (int)((kbits >> (2 * i)) & 3ull);
    if (kind == 0) {
      const float* st = hcs_state + ((size_t)(i * BATCH + b) * H + c) * 6;
      const float* hh = hcs_h + ((size_t)i * H + c) * 7;
      float acc = 0.f;
#pragma unroll
      for (int k = 0; k < 6; k++) acc += st[k] * hh[k];
      mix0[idx] = acc + hcs_D[i * H + c];
      if (b == 0) mix1[i * H + c] = hh[6];
    } else if (kind == 2) {
      const float* ii = iir + ((size_t)(i * BATCH + b) * H + c) * 16;
      const float* lpp = lp + ((size_t)i * H + c) * 16;
      const float* rs = resd + ((size_t)i * H + c) * 16;
      float acc = 0.f, rsum = 0.f;
#pragma unroll
      for (int k = 0; k < 16; k++) { float rv = rs[k]; acc += rv * expf(lpp[k]) * ii[k]; rsum += rv; }
      mix0[idx] = acc;
      if (b == 0) mix1[i * H + c] = rsum + hcl_D[i * H + c];
    }
  } else if (blk < 5632) {
    int w = tid >> 6, lane = tid & 63;
    int widx = (blk - 1024) * 4 + w;
    if (widx < 9 * BATCH * H) {
      int li = widx >> 11;
      int r = widx & 2047;
      int b = r >> 10, c = r & 1023;
      int i = (li >> 1) * 7 + ((li & 1) ? 5 : 1);
      const float* st = hcm_state + ((size_t)(i * BATCH + b) * H + c) * 127;
      const float* hh = hcm_h + ((size_t)i * H + c) * 128;
      float acc = 0.f;
      int k = lane;
      if (k < 127) acc += st[k] * hh[127 - k];
      k = lane + 64;
      if (k < 127) acc += st[k] * hh[127 - k];
      acc = wredSum(acc);
      if (lane == 0) {
        mix0[(i * BATCH + b) * H + c] = acc;
        if (b == 0) mix1[i * H + c] = hh[0] + hcm_D[i * H + c];
      }
    }
  } else {
    int idx = (blk - 5632) * 256 + tid;
    if (idx < BAR_INTS) bar[idx] = 0;
  }
}

// ---------------------------------------------------------------------------
extern "C" void kernel_launch(void* const* d_in, const int* in_sizes, int n_in,
                              void* d_out, int out_size, void* d_ws, size_t ws_size,
                              hipStream_t stream) {
  (void)in_sizes; (void)n_in; (void)out_size; (void)ws_size;
  const float* x0    = (const float*)d_in[0];
  const int*   posp  = (const int*)d_in[1];
  const float* n1    = (const float*)d_in[2];
  const float* n2    = (const float*)d_in[3];
  const float* pW    = (const float*)d_in[4];
  const float* pb    = (const float*)d_in[5];
  const float* oW    = (const float*)d_in[6];
  const float* ob    = (const float*)d_in[7];
  const float* W1    = (const float*)d_in[8];
  const float* W2    = (const float*)d_in[9];
  const float* sfw   = (const float*)d_in[10];
  const float* sfb   = (const float*)d_in[11];
  const float* hcs_h = (const float*)d_in[12];
  const float* hcs_D = (const float*)d_in[13];
  const float* hcm_h = (const float*)d_in[14];
  const float* hcm_D = (const float*)d_in[15];
  const float* lp    = (const float*)d_in[16];
  const float* resd  = (const float*)d_in[17];
  const float* hclD  = (const float*)d_in[18];
  const float* fir   = (const float*)d_in[19];
  const float* hcsS  = (const float*)d_in[20];
  const float* hcmS  = (const float*)d_in[21];
  const float* iir   = (const float*)d_in[22];
  const float* kc    = (const float*)d_in[23];
  const float* vc    = (const float*)d_in[24];
  const float* cosT  = (const float*)d_in[25];
  const float* sinT  = (const float*)d_in[26];

  float* ws   = (float*)d_ws;
  float* xA   = ws;                  // 2048
  float* xB   = ws + 2048;           // 2048
  float* xM   = ws + 4096;           // 2048
  float* zb   = ws + 6144;           // 6144
  float* yb   = ws + 12288;          // 2048
  float* hb   = ws + 14336;          // 4096
  float* attP = ws + 18432;          // 33792
  float* sfd  = ws + 52224;          // 196608
  float* sfc  = ws + 248832;         // 98304
  float* mix0 = ws + 347136;         // 65536
  float* mix1 = ws + 412672;         // 32768
  int*   bar  = (int*)(ws + 445440); // BAR_INTS = 8320 ints

  static const int KIND[LAYERS] = {0,1,2,3,0,1,2,0,1,2,3,0,1,2,0,1,2,3,0,1,2,0,1,2,3,0,1,2,0,1,2,3};
  unsigned long long kbits = 0ull;
  for (int i = 0; i < LAYERS; i++) kbits |= ((unsigned long long)KIND[i]) << (2 * i);

  int zblocks = (BAR_INTS + 255) / 256;  // 33
  prep_kernel<<<5632 + zblocks, 256, 0, stream>>>(sfw, sfb, fir, hcs_h, hcs_D, hcsS,
      hcm_h, hcm_D, hcmS, lp, resd, hclD, iir, kbits, sfd, sfc, mix0, mix1, bar);

  int occ = 0;
  hipError_t oe = hipOccupancyMaxActiveBlocksPerMultiprocessor(&occ, mega, 512, 0);
  if (oe != hipSuccess || occ < 1) occ = 1;
  int nwg = occ * 256;
  if (nwg > 512) nwg = 512;

  MegaArgs ma;
  ma.x0 = x0; ma.posp = posp; ma.n1 = n1; ma.n2 = n2;
  ma.pW = pW; ma.pb = pb; ma.oW = oW; ma.ob = ob; ma.W1 = W1; ma.W2 = W2;
  ma.sfc = sfc; ma.sfd = sfd; ma.mix0 = mix0; ma.mix1 = mix1;
  ma.kc = kc; ma.vc = vc; ma.cosT = cosT; ma.sinT = sinT;
  ma.z = zb; ma.y = yb; ma.xA = xA; ma.xB = xB; ma.xM = xM; ma.h = hb; ma.attP = attP;
  ma.bar = bar; ma.out = (float*)d_out; ma.nwg = nwg;

  void* kp[] = { &ma };
  hipLaunchCooperativeKernel(mega, dim3(nwg), dim3(512), kp, 0, stream);
}

// Round 5
// 1178.395 us; speedup vs baseline: 2.2859x; 2.2851x over previous
//
#include <hip/hip_runtime.h>
#include <hip/hip_bf16.h>
#include <math.h>

#define LAYERS 32
#define H      1024
#define H3     3072
#define NHEADS 16
#define HDIM   64
#define FF     2048
#define BATCH  2
#define SEQ    2048
#define EPSF   1e-6f
#define SCALE_D   17592186044416.0        // 2^44
#define INV_SCALE 5.684341886080802e-14   // 2^-44

__device__ __forceinline__ float wredSum(float v) {
#pragma unroll
  for (int m = 32; m >= 1; m >>= 1) v += __shfl_xor(v, m, 64);
  return v;
}
__device__ __forceinline__ float wredMax(float v) {
#pragma unroll
  for (int m = 32; m >= 1; m >>= 1) v = fmaxf(v, __shfl_xor(v, m, 64));
  return v;
}
__device__ __forceinline__ float gelu_t(float x) {
  return 0.5f * x * (1.0f + tanhf(0.7978845608028654f * (x + 0.044715f * x * x * x)));
}
// x for layer i>0 is (fixed-point MLP accumulator) * 2^-44 + xM (pre-MLP residual)
__device__ __forceinline__ float combineX(const unsigned long long* accP, const float* xMP,
                                          const float* x0f, int first, int e) {
  if (first) return x0f[e];
  return (float)((double)(long long)accP[e] * INV_SCALE) + xMP[e];
}

// ---------------------------------------------------------------------------
// prep: hoist all state-linear terms (r1-verified).
// ---------------------------------------------------------------------------
__global__ __launch_bounds__(256) void prep_kernel(
    const float* __restrict__ sf_w, const float* __restrict__ sf_b,
    const float* __restrict__ fir_state,
    const float* __restrict__ hcs_h, const float* __restrict__ hcs_D, const float* __restrict__ hcs_state,
    const float* __restrict__ hcm_h, const float* __restrict__ hcm_D, const float* __restrict__ hcm_state,
    const float* __restrict__ lp, const float* __restrict__ resd, const float* __restrict__ hcl_D,
    const float* __restrict__ iir,
    unsigned long long kbits,
    float* __restrict__ sfd, float* __restrict__ sfc,
    float* __restrict__ mix0, float* __restrict__ mix1)
{
  int blk = blockIdx.x, tid = threadIdx.x;
  if (blk < 768) {
    int idx = blk * 256 + tid;
    int i = idx / (BATCH * H3);
    int r = idx % (BATCH * H3);
    int b = r / H3, ch = r % H3;
    const float* fs = fir_state + ((size_t)(i * BATCH + b) * H3 + ch) * 2;
    const float* sw = sf_w + ((size_t)i * H3 + ch) * 3;
    sfd[idx] = fs[0] * sw[0] + fs[1] * sw[1] + sf_b[i * H3 + ch];
    if (b == 0) sfc[i * H3 + ch] = sw[2];
  } else if (blk < 1024) {
    int idx = (blk - 768) * 256 + tid;
    int i = idx >> 11;
    int r = idx & 2047;
    int b = r >> 10, c = r & 1023;
    int kind = (int)((kbits >> (2 * i)) & 3ull);
    if (kind == 0) {
      const float* st = hcs_state + ((size_t)(i * BATCH + b) * H + c) * 6;
      const float* hh = hcs_h + ((size_t)i * H + c) * 7;
      float acc = 0.f;
#pragma unroll
      for (int k = 0; k < 6; k++) acc += st[k] * hh[k];
      mix0[idx] = acc + hcs_D[i * H + c];
      if (b == 0) mix1[i * H + c] = hh[6];
    } else if (kind == 2) {
      const float* ii = iir + ((size_t)(i * BATCH + b) * H + c) * 16;
      const float* lpp = lp + ((size_t)i * H + c) * 16;
      const float* rs = resd + ((size_t)i * H + c) * 16;
      float acc = 0.f, rsum = 0.f;
#pragma unroll
      for (int k = 0; k < 16; k++) { float rv = rs[k]; acc += rv * expf(lpp[k]) * ii[k]; rsum += rv; }
      mix0[idx] = acc;
      if (b == 0) mix1[i * H + c] = rsum + hcl_D[i * H + c];
    }
  } else {
    int w = tid >> 6, lane = tid & 63;
    int widx = (blk - 1024) * 4 + w;
    if (widx < 9 * BATCH * H) {
      int li = widx >> 11;
      int r = widx & 2047;
      int b = r >> 10, c = r & 1023;
      int i = (li >> 1) * 7 + ((li & 1) ? 5 : 1);  // HCM layers 1,5,8,12,15,19,22,26,29
      const float* st = hcm_state + ((size_t)(i * BATCH + b) * H + c) * 127;
      const float* hh = hcm_h + ((size_t)i * H + c) * 128;
      float acc = 0.f;
      int k = lane;
      if (k < 127) acc += st[k] * hh[127 - k];
      k = lane + 64;
      if (k < 127) acc += st[k] * hh[127 - k];
      acc = wredSum(acc);
      if (lane == 0) {
        mix0[(i * BATCH + b) * H + c] = acc;
        if (b == 0) mix1[i * H + c] = hh[0] + hcm_D[i * H + c];
      }
    }
  }
}

// ---------------------------------------------------------------------------
// P stage: fused rmsnorm(combine-x) + proj GEMV -> z.  8 rows/block.
// Also zeroes this layer's MLP accumulator (blocks 0..7).
// ---------------------------------------------------------------------------
__global__ __launch_bounds__(256) void gemv_P(
    const unsigned long long* __restrict__ accP, const float* __restrict__ xMP,
    const float* __restrict__ x0f, int first,
    const float* __restrict__ nw, const float* __restrict__ W,
    const float* __restrict__ bias, float* __restrict__ out,
    unsigned long long* __restrict__ accZ)
{
  __shared__ alignas(16) float xe[BATCH][H];
  __shared__ float red[8];
  __shared__ float scl[BATCH];
  int tid = threadIdx.x, lane = tid & 63, w = tid >> 6;
  if (blockIdx.x < 8) accZ[blockIdx.x * 256 + tid] = 0ull;
  int r0 = blockIdx.x * 8 + w * 2;
  const float4* row0 = (const float4*)(W + (size_t)r0 * H);
  const float4* row1 = (const float4*)(W + (size_t)(r0 + 1) * H);
  float4 wa[4], wb[4];
#pragma unroll
  for (int j = 0; j < 4; j++) { wa[j] = row0[lane + 64 * j]; wb[j] = row1[lane + 64 * j]; }

  float ss0 = 0.f, ss1 = 0.f;
#pragma unroll
  for (int it = 0; it < 8; it++) {
    int e = tid + it * 256;
    int b = e >> 10, c = e & 1023;
    float xv = combineX(accP, xMP, x0f, first, e);
    xe[b][c] = xv * nw[c];
    if (it < 4) ss0 += xv * xv; else ss1 += xv * xv;
  }
  ss0 = wredSum(ss0); ss1 = wredSum(ss1);
  if (lane == 0) { red[w] = ss0; red[4 + w] = ss1; }
  __syncthreads();
  if (tid == 0) {
    scl[0] = rsqrtf((red[0] + red[1] + red[2] + red[3]) * (1.0f / H) + EPSF);
    scl[1] = rsqrtf((red[4] + red[5] + red[6] + red[7]) * (1.0f / H) + EPSF);
  }
  __syncthreads();

  float a00 = 0.f, a01 = 0.f, a10 = 0.f, a11 = 0.f;
  const float4* x0v = (const float4*)xe[0];
  const float4* x1v = (const float4*)xe[1];
#pragma unroll
  for (int j = 0; j < 4; j++) {
    float4 h0 = x0v[lane + 64 * j], h1 = x1v[lane + 64 * j];
    a00 += wa[j].x * h0.x + wa[j].y * h0.y + wa[j].z * h0.z + wa[j].w * h0.w;
    a01 += wa[j].x * h1.x + wa[j].y * h1.y + wa[j].z * h1.z + wa[j].w * h1.w;
    a10 += wb[j].x * h0.x + wb[j].y * h0.y + wb[j].z * h0.z + wb[j].w * h0.w;
    a11 += wb[j].x * h1.x + wb[j].y * h1.y + wb[j].z * h1.z + wb[j].w * h1.w;
  }
  a00 = wredSum(a00); a01 = wredSum(a01); a10 = wredSum(a10); a11 = wredSum(a11);
  if (lane == 0) {
    float s0 = scl[0], s1 = scl[1];
    float b0 = bias[r0], b1 = bias[r0 + 1];
    out[0 * H3 + r0]     = a00 * s0 + b0;
    out[1 * H3 + r0]     = a01 * s1 + b0;
    out[0 * H3 + r0 + 1] = a10 * s0 + b1;
    out[1 * H3 + r0 + 1] = a11 * s1 + b1;
  }
}

// ---------------------------------------------------------------------------
// mixer (redundant per block) + out_W GEMV + bias + residual -> xM
// ---------------------------------------------------------------------------
__global__ __launch_bounds__(256) void mix_out_kernel(
    int kind,
    const float* __restrict__ z, const float* __restrict__ sfdL, const float* __restrict__ sfcL,
    const float* __restrict__ mix0L, const float* __restrict__ mix1L,
    const float* __restrict__ attP,
    const float* __restrict__ oW, const float* __restrict__ ob,
    const unsigned long long* __restrict__ accP, const float* __restrict__ xMP,
    const float* __restrict__ x0f, int first,
    float* __restrict__ x_out)
{
  __shared__ alignas(16) float y[BATCH][H];
  int tid = threadIdx.x, lane = tid & 63, w = tid >> 6;
  int r0 = blockIdx.x * 8 + w * 2;
  const float4* row0 = (const float4*)(oW + (size_t)r0 * H);
  const float4* row1 = (const float4*)(oW + (size_t)(r0 + 1) * H);
  float4 wa[4], wb[4];
#pragma unroll
  for (int j = 0; j < 4; j++) { wa[j] = row0[lane + 64 * j]; wb[j] = row1[lane + 64 * j]; }

  if (kind < 3) {
#pragma unroll
    for (int it = 0; it < 8; it++) {
      int e = tid + it * 256;
      int b = e >> 10, c = e & 1023;
      int n = c >> 6, d = c & 63;
      int base = n * 192 + d;
      float x2 = sfcL[base] * z[b * H3 + base] + sfdL[b * H3 + base];
      float x1 = sfcL[base + 64] * z[b * H3 + base + 64] + sfdL[b * H3 + base + 64];
      float vv = sfcL[base + 128] * z[b * H3 + base + 128] + sfdL[b * H3 + base + 128];
      float t = x1 * vv;
      y[b][c] = (mix1L[c] * t + mix0L[b * H + c]) * x2;
    }
  } else {
#pragma unroll
    for (int it = 0; it < 8; it++) {
      int e = tid + it * 256;
      int b = e >> 10, c = e & 1023;
      int n = c >> 6, d = c & 63;
      float M = -1e30f;
#pragma unroll
      for (int sp = 0; sp < 8; sp++) M = fmaxf(M, attP[((sp * BATCH + b) * NHEADS + n) * 66 + 64]);
      float Ls = 0.f, num = 0.f;
#pragma unroll
      for (int sp = 0; sp < 8; sp++) {
        const float* P = attP + ((sp * BATCH + b) * NHEADS + n) * 66;
        float wgt = expf(P[64] - M);
        Ls += wgt * P[65];
        num += wgt * P[d];
      }
      y[b][c] = num / Ls;
    }
  }
  __syncthreads();

  float a00 = 0.f, a01 = 0.f, a10 = 0.f, a11 = 0.f;
  const float4* y0 = (const float4*)y[0];
  const float4* y1 = (const float4*)y[1];
#pragma unroll
  for (int j = 0; j < 4; j++) {
    float4 h0 = y0[lane + 64 * j], h1 = y1[lane + 64 * j];
    a00 += wa[j].x * h0.x + wa[j].y * h0.y + wa[j].z * h0.z + wa[j].w * h0.w;
    a01 += wa[j].x * h1.x + wa[j].y * h1.y + wa[j].z * h1.z + wa[j].w * h1.w;
    a10 += wb[j].x * h0.x + wb[j].y * h0.y + wb[j].z * h0.z + wb[j].w * h0.w;
    a11 += wb[j].x * h1.x + wb[j].y * h1.y + wb[j].z * h1.z + wb[j].w * h1.w;
  }
  a00 = wredSum(a00); a01 = wredSum(a01); a10 = wredSum(a10); a11 = wredSum(a11);
  if (lane == 0) {
    x_out[0 * H + r0]     = a00 + ob[r0]     + combineX(accP, xMP, x0f, first, 0 * H + r0);
    x_out[1 * H + r0]     = a01 + ob[r0]     + combineX(accP, xMP, x0f, first, 1 * H + r0);
    x_out[0 * H + r0 + 1] = a10 + ob[r0 + 1] + combineX(accP, xMP, x0f, first, 0 * H + r0 + 1);
    x_out[1 * H + r0 + 1] = a11 + ob[r0 + 1] + combineX(accP, xMP, x0f, first, 1 * H + r0 + 1);
  }
}

// ---------------------------------------------------------------------------
// fused MLP: block owns 16 consecutive FF channels.
// norm(xM) -> W1 rows (16) -> gelu (LDS) -> W2 column-slice (64B granules,
// fully coalesced) -> deterministic fixed-point i64 atomicAdd into acc.
// ---------------------------------------------------------------------------
__global__ __launch_bounds__(256) void mlp_fused(
    const float* __restrict__ xM, const float* __restrict__ nw,
    const float* __restrict__ W1, const float* __restrict__ W2,
    unsigned long long* __restrict__ acc)
{
  __shared__ alignas(16) float xe[BATCH][H];
  __shared__ float red[8];
  __shared__ float scl[BATCH];
  __shared__ float gh[BATCH][16];
  int tid = threadIdx.x, lane = tid & 63, w = tid >> 6;
  int f0 = blockIdx.x * 16;

  float ss0 = 0.f, ss1 = 0.f;
#pragma unroll
  for (int it = 0; it < 8; it++) {
    int e = tid + it * 256;
    int b = e >> 10, c = e & 1023;
    float xv = xM[e];
    xe[b][c] = xv * nw[c];
    if (it < 4) ss0 += xv * xv; else ss1 += xv * xv;
  }
  ss0 = wredSum(ss0); ss1 = wredSum(ss1);
  if (lane == 0) { red[w] = ss0; red[4 + w] = ss1; }
  __syncthreads();
  if (tid == 0) {
    scl[0] = rsqrtf((red[0] + red[1] + red[2] + red[3]) * (1.0f / H) + EPSF);
    scl[1] = rsqrtf((red[4] + red[5] + red[6] + red[7]) * (1.0f / H) + EPSF);
  }
  __syncthreads();

  // W1 phase: wave w, pass p -> rows f0 + p*8 + w*2 (+1)
#pragma unroll
  for (int p = 0; p < 2; p++) {
    int fr = p * 8 + w * 2;
    const float4* row0 = (const float4*)(W1 + (size_t)(f0 + fr) * H);
    const float4* row1 = (const float4*)(W1 + (size_t)(f0 + fr + 1) * H);
    float4 wa[4], wb[4];
#pragma unroll
    for (int j = 0; j < 4; j++) { wa[j] = row0[lane + 64 * j]; wb[j] = row1[lane + 64 * j]; }
    float a00 = 0.f, a01 = 0.f, a10 = 0.f, a11 = 0.f;
    const float4* x0v = (const float4*)xe[0];
    const float4* x1v = (const float4*)xe[1];
#pragma unroll
    for (int j = 0; j < 4; j++) {
      float4 h0 = x0v[lane + 64 * j], h1 = x1v[lane + 64 * j];
      a00 += wa[j].x * h0.x + wa[j].y * h0.y + wa[j].z * h0.z + wa[j].w * h0.w;
      a01 += wa[j].x * h1.x + wa[j].y * h1.y + wa[j].z * h1.z + wa[j].w * h1.w;
      a10 += wb[j].x * h0.x + wb[j].y * h0.y + wb[j].z * h0.z + wb[j].w * h0.w;
      a11 += wb[j].x * h1.x + wb[j].y * h1.y + wb[j].z * h1.z + wb[j].w * h1.w;
    }
    a00 = wredSum(a00); a01 = wredSum(a01); a10 = wredSum(a10); a11 = wredSum(a11);
    if (lane == 0) {
      gh[0][fr]     = gelu_t(a00 * scl[0]);
      gh[1][fr]     = gelu_t(a01 * scl[1]);
      gh[0][fr + 1] = gelu_t(a10 * scl[0]);
      gh[1][fr + 1] = gelu_t(a11 * scl[1]);
    }
  }
  __syncthreads();

  // W2 phase: quad q handles row r = it*64+q; part = lane&3 reads 16B of the
  // 64B slice W2[r][f0..f0+16) -> quad-reduce -> i64 fixed-point atomic.
  int q = tid >> 2, part = tid & 3;
  float g00 = gh[0][part * 4 + 0], g01 = gh[0][part * 4 + 1],
        g02 = gh[0][part * 4 + 2], g03 = gh[0][part * 4 + 3];
  float g10 = gh[1][part * 4 + 0], g11 = gh[1][part * 4 + 1],
        g12 = gh[1][part * 4 + 2], g13 = gh[1][part * 4 + 3];
#pragma unroll 4
  for (int it = 0; it < 16; it++) {
    int r = it * 64 + q;
    float4 wv = *(const float4*)(W2 + (size_t)r * FF + f0 + part * 4);
    float d0 = wv.x * g00 + wv.y * g01 + wv.z * g02 + wv.w * g03;
    float d1 = wv.x * g10 + wv.y * g11 + wv.z * g12 + wv.w * g13;
    d0 += __shfl_xor(d0, 1, 64); d0 += __shfl_xor(d0, 2, 64);
    d1 += __shfl_xor(d1, 1, 64); d1 += __shfl_xor(d1, 2, 64);
    if (part == 0) {
      atomicAdd(&acc[r],        (unsigned long long)(long long)llrint((double)d0 * SCALE_D));
      atomicAdd(&acc[H + r],    (unsigned long long)(long long)llrint((double)d1 * SCALE_D));
    }
  }
}

// ---------------------------------------------------------------------------
// flash-decode attention partials (r1-verified): 8 splits x 16 heads x 2 batch
// ---------------------------------------------------------------------------
__global__ __launch_bounds__(256) void attn_kernel(
    const float* __restrict__ z, const int* __restrict__ posp,
    const float* __restrict__ kc, const float* __restrict__ vc,
    const float* __restrict__ cosT, const float* __restrict__ sinT,
    float* __restrict__ P)
{
  int sp = blockIdx.x & 7, n = (blockIdx.x >> 3) & 15, b = blockIdx.x >> 7;
  int pos = *posp;
  __shared__ alignas(16) float q_s[HDIM], k_s[HDIM], v_s[HDIM];
  __shared__ float eg[256];
  __shared__ float redA[4];
  __shared__ alignas(16) float osum[4][HDIM];
  int tid = threadIdx.x, lane = tid & 63, w = tid >> 6;

  if (tid < 64) {
    int d = tid, j = d & 31;
    float cs = cosT[pos * 32 + j], sn = sinT[pos * 32 + j];
    float qv = z[b * H3 + n * 64 + d];
    float qo = z[b * H3 + n * 64 + ((d + 32) & 63)];
    q_s[d] = ((d < 32) ? (qv * cs - qo * sn) : (qv * cs + qo * sn)) * 0.125f;
    float kv = z[b * H3 + 1024 + n * 64 + d];
    float ko = z[b * H3 + 1024 + n * 64 + ((d + 32) & 63)];
    k_s[d] = (d < 32) ? (kv * cs - ko * sn) : (kv * cs + ko * sn);
    v_s[d] = z[b * H3 + 2048 + n * 64 + d];
  }
  __syncthreads();

  int s = sp * 256 + tid;
  float logit = -1e30f;
  if (s <= pos) {
    const float4* k4 = (s == pos) ? (const float4*)k_s
                                  : (const float4*)(kc + (((size_t)b * SEQ + s) * NHEADS + n) * HDIM);
    const float4* q4 = (const float4*)q_s;
    float acc = 0.f;
#pragma unroll
    for (int j = 0; j < 16; j++) {
      float4 kk = k4[j], qq = q4[j];
      acc += kk.x * qq.x + kk.y * qq.y + kk.z * qq.z + kk.w * qq.w;
    }
    logit = acc;
  }
  float m = wredMax(logit);
  if (lane == 0) redA[w] = m;
  __syncthreads();
  m = fmaxf(fmaxf(redA[0], redA[1]), fmaxf(redA[2], redA[3]));
  float e = (s <= pos) ? expf(logit - m) : 0.f;
  eg[tid] = e;
  float ps = wredSum(e);
  __syncthreads();
  if (lane == 0) redA[w] = ps;
  __syncthreads();
  float lsum = redA[0] + redA[1] + redA[2] + redA[3];

  int dgrp = lane & 15, srow = lane >> 4;
  float4 acc = make_float4(0.f, 0.f, 0.f, 0.f);
#pragma unroll 4
  for (int it = 0; it < 16; it++) {
    int sl = w * 64 + it * 4;
    if (sp * 256 + sl > pos) break;              // uniform within wave
    int sli = sl + srow;
    int ss = sp * 256 + sli;
    float ev = eg[sli];
    const float4* v4 = (ss == pos) ? (const float4*)v_s
                                   : (const float4*)(vc + (((size_t)b * SEQ + ss) * NHEADS + n) * HDIM);
    float4 vv = v4[dgrp];
    acc.x += ev * vv.x; acc.y += ev * vv.y; acc.z += ev * vv.z; acc.w += ev * vv.w;
  }
#pragma unroll
  for (int mm = 16; mm <= 32; mm <<= 1) {
    acc.x += __shfl_xor(acc.x, mm, 64);
    acc.y += __shfl_xor(acc.y, mm, 64);
    acc.z += __shfl_xor(acc.z, mm, 64);
    acc.w += __shfl_xor(acc.w, mm, 64);
  }
  if (srow == 0) ((float4*)osum[w])[dgrp] = acc;
  __syncthreads();
  float* Pp = P + ((size_t)(sp * BATCH + b) * NHEADS + n) * 66;
  if (tid < 64) Pp[tid] = osum[0][tid] + osum[1][tid] + osum[2][tid] + osum[3][tid];
  if (tid == 64) Pp[64] = m;
  if (tid == 65) Pp[65] = lsum;
}

// ---------------------------------------------------------------------------
__global__ __launch_bounds__(256) void finalize_k(
    const unsigned long long* __restrict__ acc, const float* __restrict__ xM,
    float* __restrict__ out)
{
  int e = blockIdx.x * 256 + threadIdx.x;
  out[e] = (float)((double)(long long)acc[e] * INV_SCALE) + xM[e];
}

// ---------------------------------------------------------------------------
extern "C" void kernel_launch(void* const* d_in, const int* in_sizes, int n_in,
                              void* d_out, int out_size, void* d_ws, size_t ws_size,
                              hipStream_t stream) {
  (void)in_sizes; (void)n_in; (void)out_size; (void)ws_size;
  const float* x0    = (const float*)d_in[0];
  const int*   posp  = (const int*)d_in[1];
  const float* n1    = (const float*)d_in[2];
  const float* n2    = (const float*)d_in[3];
  const float* pW    = (const float*)d_in[4];
  const float* pb    = (const float*)d_in[5];
  const float* oW    = (const float*)d_in[6];
  const float* ob    = (const float*)d_in[7];
  const float* W1    = (const float*)d_in[8];
  const float* W2    = (const float*)d_in[9];
  const float* sfw   = (const float*)d_in[10];
  const float* sfb   = (const float*)d_in[11];
  const float* hcs_h = (const float*)d_in[12];
  const float* hcs_D = (const float*)d_in[13];
  const float* hcm_h = (const float*)d_in[14];
  const float* hcm_D = (const float*)d_in[15];
  const float* lp    = (const float*)d_in[16];
  const float* resd  = (const float*)d_in[17];
  const float* hclD  = (const float*)d_in[18];
  const float* fir   = (const float*)d_in[19];
  const float* hcsS  = (const float*)d_in[20];
  const float* hcmS  = (const float*)d_in[21];
  const float* iir   = (const float*)d_in[22];
  const float* kc    = (const float*)d_in[23];
  const float* vc    = (const float*)d_in[24];
  const float* cosT  = (const float*)d_in[25];
  const float* sinT  = (const float*)d_in[26];

  float* ws    = (float*)d_ws;
  float* zbuf  = ws;                         // 6144
  float* attP  = ws + 6144;                  // 16896
  float* xM0   = ws + 23040;                 // 2048
  float* xM1   = ws + 25088;                 // 2048
  unsigned long long* acc0 = (unsigned long long*)(ws + 27136);  // 2048 u64 (4096 f)
  unsigned long long* acc1 = (unsigned long long*)(ws + 31232);  // 2048 u64
  float* sfd   = ws + 35328;                 // 196608
  float* sfc   = ws + 231936;                // 98304
  float* mix0  = ws + 330240;                // 65536
  float* mix1  = ws + 395776;                // 32768

  static const int KIND[LAYERS] = {0,1,2,3,0,1,2,0,1,2,3,0,1,2,0,1,2,3,0,1,2,0,1,2,3,0,1,2,0,1,2,3};
  unsigned long long kbits = 0ull;
  for (int i = 0; i < LAYERS; i++) kbits |= ((unsigned long long)KIND[i]) << (2 * i);

  prep_kernel<<<5632, 256, 0, stream>>>(sfw, sfb, fir, hcs_h, hcs_D, hcsS,
      hcm_h, hcm_D, hcmS, lp, resd, hclD, iir, kbits, sfd, sfc, mix0, mix1);

  const unsigned long long* accP = nullptr;
  const float* xMP = nullptr;
  int first = 1, att = 0;
  for (int i = 0; i < LAYERS; i++) {
    unsigned long long* accW = (i & 1) ? acc1 : acc0;
    float* xMW = (i & 1) ? xM1 : xM0;
    gemv_P<<<H3 / 8, 256, 0, stream>>>(
        accP, xMP, x0, first, n1 + i * H, pW + (size_t)i * H3 * H, pb + i * H3, zbuf, accW);
    if (KIND[i] == 3) {
      attn_kernel<<<256, 256, 0, stream>>>(
          zbuf, posp, kc + (size_t)att * BATCH * SEQ * NHEADS * HDIM,
          vc + (size_t)att * BATCH * SEQ * NHEADS * HDIM, cosT, sinT, attP);
      att++;
    }
    mix_out_kernel<<<H / 8, 256, 0, stream>>>(
        KIND[i], zbuf, sfd + (size_t)i * BATCH * H3, sfc + (size_t)i * H3,
        mix0 + (size_t)i * BATCH * H, mix1 + (size_t)i * H, attP,
        oW + (size_t)i * H * H, ob + i * H, accP, xMP, x0, first, xMW);
    mlp_fused<<<FF / 16, 256, 0, stream>>>(
        xMW, n2 + i * H, W1 + (size_t)i * FF * H, W2 + (size_t)i * H * FF, accW);
    accP = accW; xMP = xMW; first = 0;
  }
  finalize_k<<<8, 256, 0, stream>>>(acc1, xM1, (float*)d_out);
}

// Round 6
// 681.086 us; speedup vs baseline: 3.9550x; 1.7302x over previous
//
#include <hip/hip_runtime.h>
#include <hip/hip_bf16.h>
#include <math.h>

#define LAYERS 32
#define H      1024
#define H3     3072
#define NHEADS 16
#define HDIM   64
#define FF     2048
#define BATCH  2
#define SEQ    2048
#define EPSF   1e-6f

__device__ __forceinline__ float wredSum(float v) {
#pragma unroll
  for (int m = 32; m >= 1; m >>= 1) v += __shfl_xor(v, m, 64);
  return v;
}
__device__ __forceinline__ float wredMax(float v) {
#pragma unroll
  for (int m = 32; m >= 1; m >>= 1) v = fmaxf(v, __shfl_xor(v, m, 64));
  return v;
}
__device__ __forceinline__ float gelu_t(float x) {
  return 0.5f * x * (1.0f + tanhf(0.7978845608028654f * (x + 0.044715f * x * x * x)));
}
__device__ __forceinline__ float dot4(float4 a, float4 b) {
  return a.x * b.x + a.y * b.y + a.z * b.z + a.w * b.w;
}

// ---------------------------------------------------------------------------
// prep: hoist all state-linear terms (r1-verified, unchanged).
// ---------------------------------------------------------------------------
__global__ __launch_bounds__(256) void prep_kernel(
    const float* __restrict__ sf_w, const float* __restrict__ sf_b,
    const float* __restrict__ fir_state,
    const float* __restrict__ hcs_h, const float* __restrict__ hcs_D, const float* __restrict__ hcs_state,
    const float* __restrict__ hcm_h, const float* __restrict__ hcm_D, const float* __restrict__ hcm_state,
    const float* __restrict__ lp, const float* __restrict__ resd, const float* __restrict__ hcl_D,
    const float* __restrict__ iir,
    unsigned long long kbits,
    float* __restrict__ sfd, float* __restrict__ sfc,
    float* __restrict__ mix0, float* __restrict__ mix1)
{
  int blk = blockIdx.x, tid = threadIdx.x;
  if (blk < 768) {
    int idx = blk * 256 + tid;
    int i = idx / (BATCH * H3);
    int r = idx % (BATCH * H3);
    int b = r / H3, ch = r % H3;
    const float* fs = fir_state + ((size_t)(i * BATCH + b) * H3 + ch) * 2;
    const float* sw = sf_w + ((size_t)i * H3 + ch) * 3;
    sfd[idx] = fs[0] * sw[0] + fs[1] * sw[1] + sf_b[i * H3 + ch];
    if (b == 0) sfc[i * H3 + ch] = sw[2];
  } else if (blk < 1024) {
    int idx = (blk - 768) * 256 + tid;
    int i = idx >> 11;
    int r = idx & 2047;
    int b = r >> 10, c = r & 1023;
    int kind = (int)((kbits >> (2 * i)) & 3ull);
    if (kind == 0) {
      const float* st = hcs_state + ((size_t)(i * BATCH + b) * H + c) * 6;
      const float* hh = hcs_h + ((size_t)i * H + c) * 7;
      float acc = 0.f;
#pragma unroll
      for (int k = 0; k < 6; k++) acc += st[k] * hh[k];
      mix0[idx] = acc + hcs_D[i * H + c];
      if (b == 0) mix1[i * H + c] = hh[6];
    } else if (kind == 2) {
      const float* ii = iir + ((size_t)(i * BATCH + b) * H + c) * 16;
      const float* lpp = lp + ((size_t)i * H + c) * 16;
      const float* rs = resd + ((size_t)i * H + c) * 16;
      float acc = 0.f, rsum = 0.f;
#pragma unroll
      for (int k = 0; k < 16; k++) { float rv = rs[k]; acc += rv * expf(lpp[k]) * ii[k]; rsum += rv; }
      mix0[idx] = acc;
      if (b == 0) mix1[i * H + c] = rsum + hcl_D[i * H + c];
    }
  } else {
    int w = tid >> 6, lane = tid & 63;
    int widx = (blk - 1024) * 4 + w;
    if (widx < 9 * BATCH * H) {
      int li = widx >> 11;
      int r = widx & 2047;
      int b = r >> 10, c = r & 1023;
      int i = (li >> 1) * 7 + ((li & 1) ? 5 : 1);  // HCM layers 1,5,8,12,15,19,22,26,29
      const float* st = hcm_state + ((size_t)(i * BATCH + b) * H + c) * 127;
      const float* hh = hcm_h + ((size_t)i * H + c) * 128;
      float acc = 0.f;
      int k = lane;
      if (k < 127) acc += st[k] * hh[127 - k];
      k = lane + 64;
      if (k < 127) acc += st[k] * hh[127 - k];
      acc = wredSum(acc);
      if (lane == 0) {
        mix0[(i * BATCH + b) * H + c] = acc;
        if (b == 0) mix1[i * H + c] = hh[0] + hcm_D[i * H + c];
      }
    }
  }
}

// ---------------------------------------------------------------------------
// P / W1: fused rmsnorm + GEMV, wave-per-row, x issued BEFORE weights.
// P: 768 blocks (4 rows each of 3072), bias, no act.
// W1: 512 blocks (4 rows each of 2048), no bias, gelu.
// ---------------------------------------------------------------------------
template<int ROWS, bool GELU, bool HASBIAS>
__global__ __launch_bounds__(256) void gemv_norm(
    const float* __restrict__ x, const float* __restrict__ nw,
    const float* __restrict__ W, const float* __restrict__ bias,
    float* __restrict__ out)
{
  __shared__ alignas(16) float xe[BATCH * H];
  __shared__ float red[8];
  int tid = threadIdx.x, lane = tid & 63, w = tid >> 6;

  // ---- issue x loads FIRST (norm depends only on these) ----
  float4 xv0 = ((const float4*)x)[tid];          // batch 0
  float4 xv1 = ((const float4*)x)[tid + 256];    // batch 1
  float4 nv  = ((const float4*)nw)[tid];
  // ---- then weight row loads (stream under norm phase) ----
  int r = blockIdx.x * 4 + w;
  const float4* rowp = (const float4*)(W + (size_t)r * H);
  float4 wv0 = rowp[lane], wv1 = rowp[lane + 64],
         wv2 = rowp[lane + 128], wv3 = rowp[lane + 192];

  float ss0 = dot4(xv0, xv0), ss1 = dot4(xv1, xv1);
  ((float4*)xe)[tid]       = make_float4(xv0.x * nv.x, xv0.y * nv.y, xv0.z * nv.z, xv0.w * nv.w);
  ((float4*)xe)[tid + 256] = make_float4(xv1.x * nv.x, xv1.y * nv.y, xv1.z * nv.z, xv1.w * nv.w);
  ss0 = wredSum(ss0); ss1 = wredSum(ss1);
  if (lane == 0) { red[w] = ss0; red[4 + w] = ss1; }
  __syncthreads();
  float s0 = rsqrtf((red[0] + red[1] + red[2] + red[3]) * (1.0f / H) + EPSF);
  float s1 = rsqrtf((red[4] + red[5] + red[6] + red[7]) * (1.0f / H) + EPSF);

  const float4* x4 = (const float4*)xe;
  float a0 = dot4(wv0, x4[lane])       + dot4(wv1, x4[lane + 64])
           + dot4(wv2, x4[lane + 128]) + dot4(wv3, x4[lane + 192]);
  float a1 = dot4(wv0, x4[lane + 256]) + dot4(wv1, x4[lane + 320])
           + dot4(wv2, x4[lane + 384]) + dot4(wv3, x4[lane + 448]);
  a0 = wredSum(a0); a1 = wredSum(a1);
  if (lane == 0) {
    float b0 = HASBIAS ? bias[r] : 0.f;
    float v0 = a0 * s0 + b0, v1 = a1 * s1 + b0;
    if (GELU) { v0 = gelu_t(v0); v1 = gelu_t(v1); }
    out[r] = v0;
    out[ROWS + r] = v1;
  }
}

// ---------------------------------------------------------------------------
// mixer (redundant per block) + out_W GEMV + bias + residual -> xM
// 256 blocks x 4 rows; mixer loads issued first, weights second.
// ---------------------------------------------------------------------------
__global__ __launch_bounds__(256) void mix_out_kernel(
    int kind,
    const float* __restrict__ z, const float* __restrict__ sfdL, const float* __restrict__ sfcL,
    const float* __restrict__ mix0L, const float* __restrict__ mix1L,
    const float* __restrict__ attP,
    const float* __restrict__ oW, const float* __restrict__ ob,
    const float* __restrict__ x_in, float* __restrict__ x_out)
{
  __shared__ alignas(16) float ys[BATCH * H];
  int tid = threadIdx.x, lane = tid & 63, w = tid >> 6;
  int r = blockIdx.x * 4 + w;

  if (kind < 3) {
    // mixer input loads (mostly L2-resident) — issued before weights
    float x2v[8], x1v[8], vvv[8];
#pragma unroll
    for (int it = 0; it < 8; it++) {
      int e = tid + it * 256;
      int b = e >> 10, c = e & 1023;
      int n = c >> 6, d = c & 63;
      int base = n * 192 + d;
      x2v[it] = sfcL[base] * z[b * H3 + base] + sfdL[b * H3 + base];
      x1v[it] = sfcL[base + 64] * z[b * H3 + base + 64] + sfdL[b * H3 + base + 64];
      vvv[it] = sfcL[base + 128] * z[b * H3 + base + 128] + sfdL[b * H3 + base + 128];
    }
    const float4* rowp = (const float4*)(oW + (size_t)r * H);
    float4 wv0 = rowp[lane], wv1 = rowp[lane + 64],
           wv2 = rowp[lane + 128], wv3 = rowp[lane + 192];
#pragma unroll
    for (int it = 0; it < 8; it++) {
      int e = tid + it * 256;
      int b = e >> 10, c = e & 1023;
      float t = x1v[it] * vvv[it];
      ys[e] = (mix1L[c] * t + mix0L[b * H + c]) * x2v[it];
    }
    __syncthreads();
    const float4* y4 = (const float4*)ys;
    float a0 = dot4(wv0, y4[lane])       + dot4(wv1, y4[lane + 64])
             + dot4(wv2, y4[lane + 128]) + dot4(wv3, y4[lane + 192]);
    float a1 = dot4(wv0, y4[lane + 256]) + dot4(wv1, y4[lane + 320])
             + dot4(wv2, y4[lane + 384]) + dot4(wv3, y4[lane + 448]);
    a0 = wredSum(a0); a1 = wredSum(a1);
    if (lane == 0) {
      x_out[r]     = a0 + ob[r] + x_in[r];
      x_out[H + r] = a1 + ob[r] + x_in[H + r];
    }
  } else {
    const float4* rowp = (const float4*)(oW + (size_t)r * H);
    float4 wv0 = rowp[lane], wv1 = rowp[lane + 64],
           wv2 = rowp[lane + 128], wv3 = rowp[lane + 192];
#pragma unroll
    for (int it = 0; it < 8; it++) {
      int e = tid + it * 256;
      int b = e >> 10, c = e & 1023;
      int n = c >> 6, d = c & 63;
      float M = -1e30f;
#pragma unroll
      for (int sp = 0; sp < 8; sp++) M = fmaxf(M, attP[((sp * BATCH + b) * NHEADS + n) * 66 + 64]);
      float Ls = 0.f, num = 0.f;
#pragma unroll
      for (int sp = 0; sp < 8; sp++) {
        const float* P = attP + ((sp * BATCH + b) * NHEADS + n) * 66;
        float wgt = expf(P[64] - M);
        Ls += wgt * P[65];
        num += wgt * P[d];
      }
      ys[e] = num / Ls;
    }
    __syncthreads();
    const float4* y4 = (const float4*)ys;
    float a0 = dot4(wv0, y4[lane])       + dot4(wv1, y4[lane + 64])
             + dot4(wv2, y4[lane + 128]) + dot4(wv3, y4[lane + 192]);
    float a1 = dot4(wv0, y4[lane + 256]) + dot4(wv1, y4[lane + 320])
             + dot4(wv2, y4[lane + 384]) + dot4(wv3, y4[lane + 448]);
    a0 = wredSum(a0); a1 = wredSum(a1);
    if (lane == 0) {
      x_out[r]     = a0 + ob[r] + x_in[r];
      x_out[H + r] = a1 + ob[r] + x_in[H + r];
    }
  }
}

// ---------------------------------------------------------------------------
// W2 GEMV + residual. 256 blocks x 4 rows (row len FF). h staged in LDS,
// h loads issued before weights.
// ---------------------------------------------------------------------------
__global__ __launch_bounds__(256) void gemv_mlp2(
    const float* __restrict__ h, const float* __restrict__ W2,
    const float* __restrict__ xM, float* __restrict__ x_out)
{
  __shared__ alignas(16) float hs[BATCH * FF];
  int tid = threadIdx.x, lane = tid & 63, w = tid >> 6;
  // h loads first
  float4 h0 = ((const float4*)h)[tid];
  float4 h1 = ((const float4*)h)[tid + 256];
  float4 h2 = ((const float4*)h)[tid + 512];
  float4 h3 = ((const float4*)h)[tid + 768];
  // weights second
  int r = blockIdx.x * 4 + w;
  const float4* rowp = (const float4*)(W2 + (size_t)r * FF);
  float4 wv[8];
#pragma unroll
  for (int j = 0; j < 8; j++) wv[j] = rowp[lane + 64 * j];

  ((float4*)hs)[tid]       = h0;
  ((float4*)hs)[tid + 256] = h1;
  ((float4*)hs)[tid + 512] = h2;
  ((float4*)hs)[tid + 768] = h3;
  __syncthreads();

  const float4* h4 = (const float4*)hs;
  float a0 = 0.f, a1 = 0.f;
#pragma unroll
  for (int j = 0; j < 8; j++) {
    a0 += dot4(wv[j], h4[lane + 64 * j]);
    a1 += dot4(wv[j], h4[lane + 64 * j + 512]);
  }
  a0 = wredSum(a0); a1 = wredSum(a1);
  if (lane == 0) {
    x_out[r]     = a0 + xM[r];
    x_out[H + r] = a1 + xM[H + r];
  }
}

// ---------------------------------------------------------------------------
// flash-decode attention partials (r1-verified): 8 splits x 16 heads x 2 batch
// ---------------------------------------------------------------------------
__global__ __launch_bounds__(256) void attn_kernel(
    const float* __restrict__ z, const int* __restrict__ posp,
    const float* __restrict__ kc, const float* __restrict__ vc,
    const float* __restrict__ cosT, const float* __restrict__ sinT,
    float* __restrict__ P)
{
  int sp = blockIdx.x & 7, n = (blockIdx.x >> 3) & 15, b = blockIdx.x >> 7;
  int pos = *posp;
  __shared__ alignas(16) float q_s[HDIM], k_s[HDIM], v_s[HDIM];
  __shared__ float eg[256];
  __shared__ float redA[4];
  __shared__ alignas(16) float osum[4][HDIM];
  int tid = threadIdx.x, lane = tid & 63, w = tid >> 6;

  if (tid < 64) {
    int d = tid, j = d & 31;
    float cs = cosT[pos * 32 + j], sn = sinT[pos * 32 + j];
    float qv = z[b * H3 + n * 64 + d];
    float qo = z[b * H3 + n * 64 + ((d + 32) & 63)];
    q_s[d] = ((d < 32) ? (qv * cs - qo * sn) : (qv * cs + qo * sn)) * 0.125f;
    float kv = z[b * H3 + 1024 + n * 64 + d];
    float ko = z[b * H3 + 1024 + n * 64 + ((d + 32) & 63)];
    k_s[d] = (d < 32) ? (kv * cs - ko * sn) : (kv * cs + ko * sn);
    v_s[d] = z[b * H3 + 2048 + n * 64 + d];
  }
  __syncthreads();

  int s = sp * 256 + tid;
  float logit = -1e30f;
  if (s <= pos) {
    const float4* k4 = (s == pos) ? (const float4*)k_s
                                  : (const float4*)(kc + (((size_t)b * SEQ + s) * NHEADS + n) * HDIM);
    const float4* q4 = (const float4*)q_s;
    float acc = 0.f;
#pragma unroll
    for (int j = 0; j < 16; j++) acc += dot4(k4[j], q4[j]);
    logit = acc;
  }
  float m = wredMax(logit);
  if (lane == 0) redA[w] = m;
  __syncthreads();
  m = fmaxf(fmaxf(redA[0], redA[1]), fmaxf(redA[2], redA[3]));
  float e = (s <= pos) ? expf(logit - m) : 0.f;
  eg[tid] = e;
  float ps = wredSum(e);
  __syncthreads();
  if (lane == 0) redA[w] = ps;
  __syncthreads();
  float lsum = redA[0] + redA[1] + redA[2] + redA[3];

  int dgrp = lane & 15, srow = lane >> 4;
  float4 acc = make_float4(0.f, 0.f, 0.f, 0.f);
#pragma unroll 4
  for (int it = 0; it < 16; it++) {
    int sl = w * 64 + it * 4;
    if (sp * 256 + sl > pos) break;              // uniform within wave
    int sli = sl + srow;
    int ss = sp * 256 + sli;
    float ev = eg[sli];
    const float4* v4 = (ss == pos) ? (const float4*)v_s
                                   : (const float4*)(vc + (((size_t)b * SEQ + ss) * NHEADS + n) * HDIM);
    float4 vv = v4[dgrp];
    acc.x += ev * vv.x; acc.y += ev * vv.y; acc.z += ev * vv.z; acc.w += ev * vv.w;
  }
#pragma unroll
  for (int mm = 16; mm <= 32; mm <<= 1) {
    acc.x += __shfl_xor(acc.x, mm, 64);
    acc.y += __shfl_xor(acc.y, mm, 64);
    acc.z += __shfl_xor(acc.z, mm, 64);
    acc.w += __shfl_xor(acc.w, mm, 64);
  }
  if (srow == 0) ((float4*)osum[w])[dgrp] = acc;
  __syncthreads();
  float* Pp = P + ((size_t)(sp * BATCH + b) * NHEADS + n) * 66;
  if (tid < 64) Pp[tid] = osum[0][tid] + osum[1][tid] + osum[2][tid] + osum[3][tid];
  if (tid == 64) Pp[64] = m;
  if (tid == 65) Pp[65] = lsum;
}

// ---------------------------------------------------------------------------
extern "C" void kernel_launch(void* const* d_in, const int* in_sizes, int n_in,
                              void* d_out, int out_size, void* d_ws, size_t ws_size,
                              hipStream_t stream) {
  (void)in_sizes; (void)n_in; (void)out_size; (void)ws_size;
  const float* x0    = (const float*)d_in[0];
  const int*   posp  = (const int*)d_in[1];
  const float* n1    = (const float*)d_in[2];
  const float* n2    = (const float*)d_in[3];
  const float* pW    = (const float*)d_in[4];
  const float* pb    = (const float*)d_in[5];
  const float* oW    = (const float*)d_in[6];
  const float* ob    = (const float*)d_in[7];
  const float* W1    = (const float*)d_in[8];
  const float* W2    = (const float*)d_in[9];
  const float* sfw   = (const float*)d_in[10];
  const float* sfb   = (const float*)d_in[11];
  const float* hcs_h = (const float*)d_in[12];
  const float* hcs_D = (const float*)d_in[13];
  const float* hcm_h = (const float*)d_in[14];
  const float* hcm_D = (const float*)d_in[15];
  const float* lp    = (const float*)d_in[16];
  const float* resd  = (const float*)d_in[17];
  const float* hclD  = (const float*)d_in[18];
  const float* fir   = (const float*)d_in[19];
  const float* hcsS  = (const float*)d_in[20];
  const float* hcmS  = (const float*)d_in[21];
  const float* iir   = (const float*)d_in[22];
  const float* kc    = (const float*)d_in[23];
  const float* vc    = (const float*)d_in[24];
  const float* cosT  = (const float*)d_in[25];
  const float* sinT  = (const float*)d_in[26];

  float* ws    = (float*)d_ws;
  float* xbuf0 = ws;                 // 2048
  float* xbuf1 = ws + 2048;          // 2048
  float* xM    = ws + 4096;          // 2048
  float* zbuf  = ws + 6144;          // 6144
  float* hbuf  = ws + 12288;         // 4096
  float* attP  = ws + 16384;         // 16896
  float* sfd   = ws + 33280;         // 196608
  float* sfc   = ws + 229888;        // 98304
  float* mix0  = ws + 328192;        // 65536
  float* mix1  = ws + 393728;        // 32768

  static const int KIND[LAYERS] = {0,1,2,3,0,1,2,0,1,2,3,0,1,2,0,1,2,3,0,1,2,0,1,2,3,0,1,2,0,1,2,3};
  unsigned long long kbits = 0ull;
  for (int i = 0; i < LAYERS; i++) kbits |= ((unsigned long long)KIND[i]) << (2 * i);

  prep_kernel<<<5632, 256, 0, stream>>>(sfw, sfb, fir, hcs_h, hcs_D, hcsS,
      hcm_h, hcm_D, hcmS, lp, resd, hclD, iir, kbits, sfd, sfc, mix0, mix1);

  const float* xsrc = x0;
  int att = 0;
  for (int i = 0; i < LAYERS; i++) {
    gemv_norm<H3, false, true><<<H3 / 4, 256, 0, stream>>>(
        xsrc, n1 + i * H, pW + (size_t)i * H3 * H, pb + i * H3, zbuf);
    if (KIND[i] == 3) {
      attn_kernel<<<256, 256, 0, stream>>>(
          zbuf, posp, kc + (size_t)att * BATCH * SEQ * NHEADS * HDIM,
          vc + (size_t)att * BATCH * SEQ * NHEADS * HDIM, cosT, sinT, attP);
      att++;
    }
    mix_out_kernel<<<H / 4, 256, 0, stream>>>(
        KIND[i], zbuf, sfd + (size_t)i * BATCH * H3, sfc + (size_t)i * H3,
        mix0 + (size_t)i * BATCH * H, mix1 + (size_t)i * H, attP,
        oW + (size_t)i * H * H, ob + i * H, xsrc, xM);
    gemv_norm<FF, true, false><<<FF / 4, 256, 0, stream>>>(
        xM, n2 + i * H, W1 + (size_t)i * FF * H, nullptr, hbuf);
    float* xout = (i == LAYERS - 1) ? (float*)d_out : ((i & 1) ? xbuf1 : xbuf0);
    gemv_mlp2<<<H / 4, 256, 0, stream>>>(
        hbuf, W2 + (size_t)i * H * FF, xM, xout);
    xsrc = xout;
  }
}